// Round 15
// baseline (304.951 us; speedup 1.0000x reference)
//
#include <hip/hip_runtime.h>
#include <cstdint>
#include <cstddef>

typedef __attribute__((ext_vector_type(8))) short bfrag;    // 8 bf16 (4 VGPR)
typedef __attribute__((ext_vector_type(4))) float f4;       // 16x16 MFMA C/D
typedef __attribute__((ext_vector_type(16))) float f16v;    // 32x32 MFMA C/D
typedef __attribute__((ext_vector_type(4))) unsigned short us4;

#define MFMA16(a, b, c) __builtin_amdgcn_mfma_f32_16x16x32_bf16(a, b, c, 0, 0, 0)
#define MFMA32(a, b, c) __builtin_amdgcn_mfma_f32_32x32x16_bf16(a, b, c, 0, 0, 0)

// ---------------------------------------------------------------------------
// fp32 -> bf16 RNE, and hi/lo split helpers
// ---------------------------------------------------------------------------
__device__ __forceinline__ unsigned short f2bf(float x) {
  unsigned u = __float_as_uint(x);
  u += 0x7fffu + ((u >> 16) & 1u);
  return (unsigned short)(u >> 16);
}
__device__ __forceinline__ float bf2f(unsigned short h) {
  return __uint_as_float(((unsigned)h) << 16);
}
// HW packed f32->2xbf16 (one instr). Rounding-mode-agnostic use: the lo
// residue compensates whatever hi rounds to.
__device__ __forceinline__ unsigned cvt_pk_bf16(float a, float b) {
  unsigned r;
  asm("v_cvt_pk_bf16_f32 %0, %1, %2" : "=v"(r) : "v"(a), "v"(b));
  return r;
}
// One-instruction cross-half exchange: a' = [a_lo | b_lo], b' = [a_hi | b_hi].
__device__ __forceinline__ void permswap(unsigned& a, unsigned& b) {
  auto r = __builtin_amdgcn_permlane32_swap((int)a, (int)b, false, false);
  a = (unsigned)r[0];
  b = (unsigned)r[1];
}
// Async global->LDS, 16B per lane. Dest is wave-uniform base + lane*16.
__device__ __forceinline__ void gl16(const unsigned short* g, unsigned short* l) {
  __builtin_amdgcn_global_load_lds(
      (const __attribute__((address_space(1))) unsigned int*)g,
      (__attribute__((address_space(3))) unsigned int*)l, 16, 0, 0);
}

// ---------------------------------------------------------------------------
// Software-exact OCP e4m3fn rounding (RTNE via magic-add; matches ml_dtypes
// bit-exact incl. subnormal grid 2^-9 and the 448-saturation region).
// ---------------------------------------------------------------------------
__device__ __forceinline__ float qd_e4m3(float v) {
  float a = fabsf(v);
  unsigned u = __float_as_uint(a);
  int e = (int)(u >> 23) - 127;
  int k = e - 3;
  if (k < -9) k = -9;
  float big = __uint_as_float((unsigned)(k + 150) << 23);  // 2^(k+23)
  float r = (a + big) - big;
  return __builtin_copysignf(r, v);
}

// ---------------------------------------------------------------------------
// Activation quant: per 128-block, emit e4m3 CODES as bf16 (exact) + scale.
// (used only for the INPUT x now; attn output quant is fused in-kernel)
// ---------------------------------------------------------------------------
__global__ __launch_bounds__(256) void quant_x(const float* __restrict__ src,
                                               unsigned short* __restrict__ q,
                                               float* __restrict__ s,
                                               int nblk) {
  int gid = blockIdx.x * 256 + threadIdx.x;
  int wid = gid >> 6;
  int lane = gid & 63;
  if (wid >= nblk) return;
  size_t off = (size_t)wid * 128 + lane * 2;
  float2 xv = *reinterpret_cast<const float2*>(src + off);
  float m = fmaxf(fabsf(xv.x), fabsf(xv.y));
#pragma unroll
  for (int d = 32; d > 0; d >>= 1) m = fmaxf(m, __shfl_xor(m, d));
  float scale = fmaxf(m / 448.0f, 1e-12f);
  unsigned short q0 = f2bf(qd_e4m3(xv.x / scale));  // exact: e4m3 ⊂ bf16
  unsigned short q1 = f2bf(qd_e4m3(xv.y / scale));
  *reinterpret_cast<unsigned*>(q + off) = (unsigned)q0 | ((unsigned)q1 << 16);
  if (lane == 0) s[wid] = scale;
}

// ---------------------------------------------------------------------------
// Weight quant + dequant + hi/lo split + TRANSPOSE: W[K,N] -> WTh/WTl[N,K].
// ---------------------------------------------------------------------------
__global__ __launch_bounds__(256) void quant_w_t(const float* __restrict__ W,
                                                 unsigned short* __restrict__ WTh,
                                                 unsigned short* __restrict__ WTl,
                                                 int K, int N) {
  __shared__ __align__(16) unsigned short Ht[128][72];
  __shared__ __align__(16) unsigned short Lt[128][72];
  const int tid = threadIdx.x;
  const int w = tid >> 6, l = tid & 63;
  const int k0 = blockIdx.y * 64, n0 = blockIdx.x * 128;
#pragma unroll 4
  for (int i = 0; i < 16; ++i) {
    int kl = w * 16 + i;
    float2 xv = *reinterpret_cast<const float2*>(&W[(size_t)(k0 + kl) * N + n0 + l * 2]);
    float m = fmaxf(fabsf(xv.x), fabsf(xv.y));
#pragma unroll
    for (int d = 32; d > 0; d >>= 1) m = fmaxf(m, __shfl_xor(m, d));
    float scale = fmaxf(m / 448.0f, 1e-12f);
    float d0 = qd_e4m3(xv.x / scale) * scale;
    float d1 = qd_e4m3(xv.y / scale) * scale;
    unsigned short h0 = f2bf(d0), h1 = f2bf(d1);
    Ht[l * 2][kl] = h0;
    Ht[l * 2 + 1][kl] = h1;
    Lt[l * 2][kl] = f2bf(d0 - bf2f(h0));
    Lt[l * 2 + 1][kl] = f2bf(d1 - bf2f(h1));
  }
  __syncthreads();
  const int arr = tid >> 7, n = tid & 127;
  const unsigned short(*T)[72] = arr ? Lt : Ht;
  unsigned short* dst = (arr ? WTl : WTh) + (size_t)(n0 + n) * K + k0;
#pragma unroll
  for (int j = 0; j < 8; ++j)
    *reinterpret_cast<bfrag*>(dst + j * 8) = *reinterpret_cast<const bfrag*>(&T[n][j * 8]);
}

// ---------------------------------------------------------------------------
// Quantization-aware MFMA GEMM (round-10 version: global_load_lds w=16 with
// both-sides XOR swizzle — measured win, unchanged).
// ---------------------------------------------------------------------------
template <bool SPLIT>
__global__ __launch_bounds__(256, 2) void gemm_q(const unsigned short* __restrict__ Aq,
                                                 const float* __restrict__ As,
                                                 const unsigned short* __restrict__ WTh,
                                                 const unsigned short* __restrict__ WTl,
                                                 const float* __restrict__ bias,
                                                 float* __restrict__ Cf,
                                                 unsigned short* __restrict__ Ch,
                                                 unsigned short* __restrict__ Cl,
                                                 int M, int N, int K) {
  __shared__ __align__(16) unsigned short Al[128][64];
  __shared__ __align__(16) unsigned short Bh[128][64];
  __shared__ __align__(16) unsigned short Bl[128][64];
  __shared__ float Ss[128][8];
  const int tid = threadIdx.x;
  const int w = tid >> 6, l = tid & 63;
  const int lr = l & 15, lg = l >> 4;
  const int nbx = N >> 7;
  const int nwg = nbx * (M >> 7);
  const int q8 = nwg >> 3;
  const int swz = ((int)blockIdx.x & 7) * q8 + ((int)blockIdx.x >> 3);
  const int row0 = (swz / nbx) << 7, col0 = (swz % nbx) << 7;
  const int wr = (w >> 1) * 64, wc = (w & 1) * 64;
  const int xsw = (lr & 7) * 8;        // read-side XOR (short units)

  {
    int r = tid >> 1, c0 = (tid & 1) * 4;
    *reinterpret_cast<float4*>(&Ss[r][c0]) =
        *reinterpret_cast<const float4*>(&As[(size_t)(row0 + r) * 8 + c0]);
  }

  f4 acc[4][4], seg[4][4];
#pragma unroll
  for (int i = 0; i < 4; ++i)
#pragma unroll
    for (int j = 0; j < 4; ++j)
#pragma unroll
      for (int c = 0; c < 4; ++c) {
        acc[i][j][c] = 0.f;
        seg[i][j][c] = 0.f;
      }

  const int lrow = l >> 3;             // 0..7
  const int jch = (l & 7) ^ lrow;      // inverse-swizzled source chunk
  const unsigned short* pA = Aq + (size_t)(row0 + w * 32 + lrow) * K + jch * 8;
  const unsigned short* pH = WTh + (size_t)(col0 + w * 32 + lrow) * K + jch * 8;
  const unsigned short* pL = WTl + (size_t)(col0 + w * 32 + lrow) * K + jch * 8;
  unsigned short* dA = &Al[0][0] + w * 2048;
  unsigned short* dH = &Bh[0][0] + w * 2048;
  unsigned short* dL = &Bl[0][0] + w * 2048;

  const int niter = K >> 6;
  for (int it = 0; it < niter; ++it) {
    const int k0 = it << 6;
    __syncthreads();
#pragma unroll
    for (int ii = 0; ii < 4; ++ii) {
      gl16(pA + (size_t)ii * 8 * K + k0, dA + ii * 512);
      gl16(pH + (size_t)ii * 8 * K + k0, dH + ii * 512);
      gl16(pL + (size_t)ii * 8 * K + k0, dL + ii * 512);
    }
    __syncthreads();

#pragma unroll
    for (int ks = 0; ks < 2; ++ks) {
      bfrag af[4];
#pragma unroll
      for (int mf = 0; mf < 4; ++mf)
        af[mf] = *reinterpret_cast<const bfrag*>(
            &Al[0][0] + (wr + mf * 16 + lr) * 64 + ((ks * 32 + lg * 8) ^ xsw));
#pragma unroll
      for (int nf = 0; nf < 4; ++nf) {
        bfrag bh = *reinterpret_cast<const bfrag*>(
            &Bh[0][0] + (wc + nf * 16 + lr) * 64 + ((ks * 32 + lg * 8) ^ xsw));
        bfrag bl = *reinterpret_cast<const bfrag*>(
            &Bl[0][0] + (wc + nf * 16 + lr) * 64 + ((ks * 32 + lg * 8) ^ xsw));
#pragma unroll
        for (int mf = 0; mf < 4; ++mf) {
          seg[mf][nf] = MFMA16(af[mf], bh, seg[mf][nf]);
          seg[mf][nf] = MFMA16(af[mf], bl, seg[mf][nf]);
        }
      }
    }

    if (it & 1) {
      const int kb = it >> 1;
#pragma unroll
      for (int mf = 0; mf < 4; ++mf) {
        float sv[4];
#pragma unroll
        for (int r = 0; r < 4; ++r) sv[r] = Ss[wr + mf * 16 + lg * 4 + r][kb];
#pragma unroll
        for (int nf = 0; nf < 4; ++nf)
#pragma unroll
          for (int r = 0; r < 4; ++r) {
            acc[mf][nf][r] += sv[r] * seg[mf][nf][r];
            seg[mf][nf][r] = 0.f;
          }
      }
    }
  }

#pragma unroll
  for (int mf = 0; mf < 4; ++mf) {
#pragma unroll
    for (int r = 0; r < 4; ++r) {
      const int m = row0 + wr + mf * 16 + lg * 4 + r;
#pragma unroll
      for (int nf = 0; nf < 4; ++nf) {
        const int col = col0 + wc + nf * 16 + lr;
        float o = acc[mf][nf][r] + bias[col];
        if (SPLIT) {
          unsigned short hh = f2bf(o);
          Ch[(size_t)m * N + col] = hh;
          Cl[(size_t)m * N + col] = f2bf(o - bf2f(hh));
        } else {
          Cf[(size_t)m * N + col] = o;
        }
      }
    }
  }
}

// ---------------------------------------------------------------------------
// Swapped-operand 32x32 MFMA flash attention + FUSED output quantization.
// Round-15 restructure: block = 2 wave-pairs x 2 heads x 64 q-rows, so each
// output row's 128-col quant block (= head pair hp) is entirely in-block.
// Epilogue computes the e4m3 block quant (bit-identical to quant_x) and
// writes CODES to xq + scales to sx; the fp32 y round-trip and the separate
// quant_x(y) launch are eliminated.
// XCD decode: xcd=lin&7, j=lin>>3, g=xcd*2+(j>>5) -> (b=g>>3, hp=g&7),
// qt2=j&31. XCD owns 2 (b,hp) groups = 4 MB KV -> L2-resident (r14 win kept).
// ---------------------------------------------------------------------------
__global__ __launch_bounds__(256, 2) void attn_mfma32(const unsigned short* __restrict__ qkvh,
                                                      const unsigned short* __restrict__ qkvl,
                                                      unsigned short* __restrict__ xq,
                                                      float* __restrict__ sx) {
  __shared__ __align__(16) unsigned short Vth[2][2][64][40];  // [buf][head][rho(d)][kpos]
  __shared__ __align__(16) unsigned short Vtl[2][2][64][40];
  __shared__ float smax[4][32];
  const int tid = threadIdx.x;
  const int w = tid >> 6, l = tid & 63;
  const int q = l & 31;
  const int hi = l >> 5;
  // XCD-aware decode
  const int lin = (int)blockIdx.x;
  const int xcd = lin & 7, jj_ = lin >> 3;
  const int g = xcd * 2 + (jj_ >> 5);
  const int qt2 = jj_ & 31;
  const int b = g >> 3, hp = g & 7;
  const int hwave = w >> 1;               // head-in-pair for this wave
  const int h = 2 * hp + hwave;
  const int qbase = qt2 * 64 + (w & 1) * 32;
  const size_t bbase = (size_t)b * 2048;
  const size_t hoff = (size_t)h * 64;

  const int rA = (q & 24) | ((q + (q >> 3)) & 7);              // d = q
  const int rB = 32 + ((q & 24) | ((q + 4 + (q >> 3)) & 7));   // d = 32+q

  bfrag qh[4], ql[4];
  {
    const size_t qrow = (bbase + qbase + q) * 3072 + hoff + hi * 8;
#pragma unroll
    for (int f = 0; f < 4; ++f) {
      qh[f] = *reinterpret_cast<const bfrag*>(qkvh + qrow + f * 16);
      ql[f] = *reinterpret_cast<const bfrag*>(qkvl + qrow + f * 16);
    }
  }

  // V staging role: threads 0-127 stage head 2hp, 128-255 stage head 2hp+1.
  const int half = tid >> 7;
  const int t128 = tid & 127;
  const int skp = t128 >> 2;   // 0..31 (kpos)
  const int sc2 = t128 & 3;    // 0..3  (d-chunk of 16)

  const unsigned short* kph = qkvh + (bbase + q) * 3072 + 1024 + hoff + hi * 8;
  const unsigned short* kpl = qkvl + (bbase + q) * 3072 + 1024 + hoff + hi * 8;
  const unsigned short* vph =
      qkvh + (bbase + skp) * 3072 + 2048 + (size_t)(2 * hp + half) * 64 + sc2 * 16;
  const unsigned short* vpl =
      qkvl + (bbase + skp) * 3072 + 2048 + (size_t)(2 * hp + half) * 64 + sc2 * 16;
  const size_t KSTEP = (size_t)32 * 3072;

  bfrag kh[4], kl[4], svh0, svh1, svl0, svl1;

#define VSTAGE_WRITE(BUF)                                                      \
  do {                                                                         \
    _Pragma("unroll") for (int j2 = 0; j2 < 8; ++j2) {                         \
      int d_ = sc2 * 16 + j2;                                                  \
      int row = (d_ & 56) | ((d_ + (d_ >> 3)) & 7);                            \
      Vth[BUF][half][row][skp] = (unsigned short)svh0[j2];                     \
      Vtl[BUF][half][row][skp] = (unsigned short)svl0[j2];                     \
    }                                                                          \
    _Pragma("unroll") for (int j2 = 0; j2 < 8; ++j2) {                         \
      int d_ = sc2 * 16 + 8 + j2;                                              \
      int row = (d_ & 56) | ((d_ + (d_ >> 3)) & 7);                            \
      Vth[BUF][half][row][skp] = (unsigned short)svh1[j2];                     \
      Vtl[BUF][half][row][skp] = (unsigned short)svl1[j2];                     \
    }                                                                          \
  } while (0)

  // ---- prologue: K(0), V(0)->LDS0, QK(0)->sA, K(1) ----
#pragma unroll
  for (int f = 0; f < 4; ++f) {
    kh[f] = *reinterpret_cast<const bfrag*>(kph + f * 16);
    kl[f] = *reinterpret_cast<const bfrag*>(kpl + f * 16);
  }
  svh0 = *reinterpret_cast<const bfrag*>(vph);
  svh1 = *reinterpret_cast<const bfrag*>(vph + 8);
  svl0 = *reinterpret_cast<const bfrag*>(vpl);
  svl1 = *reinterpret_cast<const bfrag*>(vpl + 8);
  vph += KSTEP; vpl += KSTEP;
  VSTAGE_WRITE(0);
  f16v sA, sB;
#pragma unroll
  for (int r = 0; r < 16; ++r) sA[r] = 0.f;
  __builtin_amdgcn_s_setprio(1);
#pragma unroll
  for (int f = 0; f < 4; ++f) sA = MFMA32(kh[f], qh[f], sA);
#pragma unroll
  for (int f = 0; f < 4; ++f) sA = MFMA32(kh[f], ql[f], sA);
#pragma unroll
  for (int f = 0; f < 4; ++f) sA = MFMA32(kl[f], qh[f], sA);
  __builtin_amdgcn_s_setprio(0);
  kph += KSTEP; kpl += KSTEP;
#pragma unroll
  for (int f = 0; f < 4; ++f) {
    kh[f] = *reinterpret_cast<const bfrag*>(kph + f * 16);
    kl[f] = *reinterpret_cast<const bfrag*>(kpl + f * 16);
  }
  __syncthreads();

  f16v oA0, oA1, oB0, oB1;
#pragma unroll
  for (int r = 0; r < 16; ++r) { oA0[r] = 0.f; oA1[r] = 0.f; oB0[r] = 0.f; oB1[r] = 0.f; }
  float m_i = -1e30f, l_i = 0.f;

#define ATTN_ITER(KT, SCUR, SNXT)                                              \
  do {                                                                         \
    const int kt_ = (KT);                                                      \
    const int cur_ = kt_ & 1;                                                  \
    /* 1: issue QK(kt+1) into SNXT (overlaps softmax below) */                 \
    if (kt_ < 63) {                                                            \
      _Pragma("unroll") for (int r = 0; r < 16; ++r) SNXT[r] = 0.f;            \
      __builtin_amdgcn_s_setprio(1);                                           \
      _Pragma("unroll") for (int f = 0; f < 4; ++f)                            \
          SNXT = MFMA32(kh[f], qh[f], SNXT);                                   \
      _Pragma("unroll") for (int f = 0; f < 4; ++f)                            \
          SNXT = MFMA32(kh[f], ql[f], SNXT);                                   \
      _Pragma("unroll") for (int f = 0; f < 4; ++f)                            \
          SNXT = MFMA32(kl[f], qh[f], SNXT);                                   \
      __builtin_amdgcn_s_setprio(0);                                           \
    }                                                                          \
    /* 2: K(kt+2) loads */                                                     \
    if (kt_ < 62) {                                                            \
      kph += KSTEP; kpl += KSTEP;                                              \
      _Pragma("unroll") for (int f = 0; f < 4; ++f) {                          \
        kh[f] = *reinterpret_cast<const bfrag*>(kph + f * 16);                 \
        kl[f] = *reinterpret_cast<const bfrag*>(kpl + f * 16);                 \
      }                                                                        \
    }                                                                          \
    /* 3: softmax on SCUR (VALU — overlaps step-1 MFMAs) */                    \
    float a0 = fmaxf(SCUR[0], SCUR[1]), a1 = fmaxf(SCUR[2], SCUR[3]);          \
    float a2 = fmaxf(SCUR[4], SCUR[5]), a3 = fmaxf(SCUR[6], SCUR[7]);          \
    float a4 = fmaxf(SCUR[8], SCUR[9]), a5 = fmaxf(SCUR[10], SCUR[11]);        \
    float a6 = fmaxf(SCUR[12], SCUR[13]), a7 = fmaxf(SCUR[14], SCUR[15]);      \
    float b0_ = fmaxf(a0, a1), b1_ = fmaxf(a2, a3);                            \
    float b2_ = fmaxf(a4, a5), b3_ = fmaxf(a6, a7);                            \
    float mt = fmaxf(fmaxf(b0_, b1_), fmaxf(b2_, b3_));                        \
    mt = fmaxf(mt, __shfl_xor(mt, 32));                                        \
    mt *= 0.125f;                                                              \
    if (!__all(mt <= m_i)) { /* defer-max: THR=0 is bit-exact */               \
      float mn = fmaxf(m_i, mt);                                               \
      float corr = __expf(m_i - mn);                                           \
      m_i = mn;                                                                \
      l_i *= corr;                                                             \
      _Pragma("unroll") for (int r = 0; r < 16; ++r) {                         \
        oA0[r] *= corr; oA1[r] *= corr; oB0[r] *= corr; oB1[r] *= corr;        \
      }                                                                        \
    }                                                                          \
    float p[16];                                                               \
    _Pragma("unroll") for (int r = 0; r < 16; ++r)                             \
        p[r] = __expf(fmaf(SCUR[r], 0.125f, -m_i));                            \
    float r0_ = (p[0] + p[1]) + (p[2] + p[3]);                                 \
    float r1_ = (p[4] + p[5]) + (p[6] + p[7]);                                 \
    float r2_ = (p[8] + p[9]) + (p[10] + p[11]);                               \
    float r3_ = (p[12] + p[13]) + (p[14] + p[15]);                             \
    float rs = (r0_ + r1_) + (r2_ + r3_);                                      \
    rs += __shfl_xor(rs, 32);                                                  \
    l_i += rs;                                                                 \
    /* 4: issue V(kt+1) load (written to LDS at step 7) */                     \
    if (kt_ < 63) {                                                            \
      svh0 = *reinterpret_cast<const bfrag*>(vph);                             \
      svh1 = *reinterpret_cast<const bfrag*>(vph + 8);                         \
      svl0 = *reinterpret_cast<const bfrag*>(vpl);                             \
      svl1 = *reinterpret_cast<const bfrag*>(vpl + 8);                         \
      vph += KSTEP; vpl += KSTEP;                                              \
    }                                                                          \
    /* 5: pack P hi/lo + permlane32_swap frag build */                         \
    unsigned ph_[8], pl_[8];                                                   \
    _Pragma("unroll") for (int i = 0; i < 8; ++i) {                            \
      unsigned hp2 = cvt_pk_bf16(p[2 * i], p[2 * i + 1]);                      \
      float e0 = p[2 * i] - __uint_as_float(hp2 << 16);                        \
      float e1 = p[2 * i + 1] - __uint_as_float(hp2 & 0xffff0000u);            \
      ph_[i] = hp2;                                                            \
      pl_[i] = cvt_pk_bf16(e0, e1);                                            \
    }                                                                          \
    permswap(ph_[0], ph_[2]); permswap(ph_[1], ph_[3]);                        \
    permswap(ph_[4], ph_[6]); permswap(ph_[5], ph_[7]);                        \
    permswap(pl_[0], pl_[2]); permswap(pl_[1], pl_[3]);                        \
    permswap(pl_[4], pl_[6]); permswap(pl_[5], pl_[7]);                        \
    union U4u { unsigned u[4]; bfrag f; };                                     \
    U4u f0h, f1h, f0l, f1l;                                                    \
    f0h.u[0] = ph_[0]; f0h.u[1] = ph_[1]; f0h.u[2] = ph_[2]; f0h.u[3] = ph_[3];\
    f1h.u[0] = ph_[4]; f1h.u[1] = ph_[5]; f1h.u[2] = ph_[6]; f1h.u[3] = ph_[7];\
    f0l.u[0] = pl_[0]; f0l.u[1] = pl_[1]; f0l.u[2] = pl_[2]; f0l.u[3] = pl_[3];\
    f1l.u[0] = pl_[4]; f1l.u[1] = pl_[5]; f1l.u[2] = pl_[6]; f1l.u[3] = pl_[7];\
    /* 6: PV(kt) from LDS[cur_][hwave], rho rows */                            \
    __builtin_amdgcn_s_setprio(1);                                             \
    _Pragma("unroll") for (int c = 0; c < 2; ++c) {                            \
      bfrag pF = c ? f1h.f : f0h.f;                                            \
      bfrag pL = c ? f1l.f : f0l.f;                                            \
      bfrag vh0 = *reinterpret_cast<const bfrag*>(&Vth[cur_][hwave][rA][c * 16 + hi * 8]); \
      bfrag vl0 = *reinterpret_cast<const bfrag*>(&Vtl[cur_][hwave][rA][c * 16 + hi * 8]); \
      bfrag vh1 = *reinterpret_cast<const bfrag*>(&Vth[cur_][hwave][rB][c * 16 + hi * 8]); \
      bfrag vl1 = *reinterpret_cast<const bfrag*>(&Vtl[cur_][hwave][rB][c * 16 + hi * 8]); \
      oA0 = MFMA32(vh0, pF, oA0);                                              \
      oB0 = MFMA32(vh0, pL, oB0);                                              \
      oB0 = MFMA32(vl0, pF, oB0);                                              \
      oA1 = MFMA32(vh1, pF, oA1);                                              \
      oB1 = MFMA32(vh1, pL, oB1);                                              \
      oB1 = MFMA32(vl1, pF, oB1);                                              \
    }                                                                          \
    __builtin_amdgcn_s_setprio(0);                                             \
    /* 7: write staged V(kt+1), barrier */                                     \
    if (kt_ < 63) {                                                            \
      VSTAGE_WRITE(cur_ ^ 1);                                                  \
      __syncthreads();                                                         \
    }                                                                          \
  } while (0)

  for (int kt = 0; kt < 64; kt += 2) {
    ATTN_ITER(kt, sA, sB);
    ATTN_ITER(kt + 1, sB, sA);
  }
#undef ATTN_ITER
#undef VSTAGE_WRITE

  // ---- fused epilogue: normalize, 128-block e4m3 quant, store codes ----
  float inv = 1.0f / l_i;
  float v0[16], v1[16];
  float mx = 0.f;
#pragma unroll
  for (int r = 0; r < 16; ++r) {
    v0[r] = (oA0[r] + oB0[r]) * inv;
    v1[r] = (oA1[r] + oB1[r]) * inv;
    mx = fmaxf(mx, fmaxf(fabsf(v0[r]), fabsf(v1[r])));
  }
  mx = fmaxf(mx, __shfl_xor(mx, 32));   // combine hi halves (same row)
  if (hi == 0) smax[w][q] = mx;
  __syncthreads();
  mx = fmaxf(mx, smax[w ^ 2][q]);       // combine the other head of the pair
  float scale = fmaxf(mx / 448.0f, 1e-12f);

  const size_t row = bbase + qbase + q;
  unsigned short* xrow = xq + row * 1024 + hoff;
#pragma unroll
  for (int rg = 0; rg < 4; ++rg) {
    us4 c0, c1;
#pragma unroll
    for (int j2 = 0; j2 < 4; ++j2) {
      c0[j2] = f2bf(qd_e4m3(v0[rg * 4 + j2] / scale));
      c1[j2] = f2bf(qd_e4m3(v1[rg * 4 + j2] / scale));
    }
    *reinterpret_cast<us4*>(xrow + rg * 8 + hi * 4) = c0;
    *reinterpret_cast<us4*>(xrow + 32 + rg * 8 + hi * 4) = c1;
  }
  if (w < 2 && hi == 0) sx[row * 8 + hp] = scale;
}

// ---------------------------------------------------------------------------
// Workspace layout (72.25 MiB) — unchanged. Attention now writes x_q/s_x
// directly (fused quant); d_out is written only by the final projection.
// ---------------------------------------------------------------------------
extern "C" void kernel_launch(void* const* d_in, const int* in_sizes, int n_in,
                              void* d_out, int out_size, void* d_ws, size_t ws_size,
                              hipStream_t stream) {
  const float* x     = (const float*)d_in[0];
  const float* W_qkv = (const float*)d_in[1];
  const float* b_qkv = (const float*)d_in[2];
  const float* W_out = (const float*)d_in[3];
  const float* b_out = (const float*)d_in[4];
  float* y = (float*)d_out;

  char* ws = (char*)d_ws;
  const size_t MB = 1u << 20;
  unsigned short* x_q   = (unsigned short*)(ws);
  float*          s_x   = (float*)(ws + 8 * MB);
  unsigned short* wqh   = (unsigned short*)(ws + 8 * MB + 256 * 1024);
  unsigned short* wql   = (unsigned short*)(ws + 14 * MB + 256 * 1024);
  unsigned short* woh   = (unsigned short*)(ws + 20 * MB + 256 * 1024);
  unsigned short* wol   = (unsigned short*)(ws + 22 * MB + 256 * 1024);
  unsigned short* qkvh  = (unsigned short*)(ws + 24 * MB + 256 * 1024);
  unsigned short* qkvl  = (unsigned short*)(ws + 48 * MB + 256 * 1024);

  // 1. quantize activations (codes + scales) and weights (split + transpose)
  quant_x<<<8192, 256, 0, stream>>>(x, x_q, s_x, 32768);
  quant_w_t<<<dim3(24, 16), 256, 0, stream>>>(W_qkv, wqh, wql, 1024, 3072);
  quant_w_t<<<dim3(8, 16), 256, 0, stream>>>(W_out, woh, wol, 1024, 1024);

  // 2. QKV projection (quant-aware MFMA, gload_lds staging) -> split bf16
  gemm_q<true><<<768, 256, 0, stream>>>(x_q, s_x, wqh, wql, b_qkv,
                                        nullptr, qkvh, qkvl, 4096, 3072, 1024);

  // 3. flash attention with FUSED output quant -> x_q / s_x directly
  attn_mfma32<<<512, 256, 0, stream>>>(qkvh, qkvl, x_q, s_x);

  // 4. output projection (quant-aware MFMA) -> fp32 d_out
  gemm_q<false><<<256, 256, 0, stream>>>(x_q, s_x, woh, wol, b_out,
                                         y, nullptr, nullptr, 4096, 1024, 1024);
}

// Round 16
// 272.259 us; speedup vs baseline: 1.1201x; 1.1201x over previous
//
#include <hip/hip_runtime.h>
#include <cstdint>
#include <cstddef>

typedef __attribute__((ext_vector_type(8))) short bfrag;    // 8 bf16 (4 VGPR)
typedef __attribute__((ext_vector_type(4))) float f4;       // 16x16 MFMA C/D
typedef __attribute__((ext_vector_type(16))) float f16v;    // 32x32 MFMA C/D

#define MFMA16(a, b, c) __builtin_amdgcn_mfma_f32_16x16x32_bf16(a, b, c, 0, 0, 0)
#define MFMA32(a, b, c) __builtin_amdgcn_mfma_f32_32x32x16_bf16(a, b, c, 0, 0, 0)

// ---------------------------------------------------------------------------
// fp32 -> bf16 RNE, and hi/lo split helpers
// ---------------------------------------------------------------------------
__device__ __forceinline__ unsigned short f2bf(float x) {
  unsigned u = __float_as_uint(x);
  u += 0x7fffu + ((u >> 16) & 1u);
  return (unsigned short)(u >> 16);
}
__device__ __forceinline__ float bf2f(unsigned short h) {
  return __uint_as_float(((unsigned)h) << 16);
}
// HW packed f32->2xbf16 (one instr). Rounding-mode-agnostic use: the lo
// residue compensates whatever hi rounds to.
__device__ __forceinline__ unsigned cvt_pk_bf16(float a, float b) {
  unsigned r;
  asm("v_cvt_pk_bf16_f32 %0, %1, %2" : "=v"(r) : "v"(a), "v"(b));
  return r;
}
// One-instruction cross-half exchange: a' = [a_lo | b_lo], b' = [a_hi | b_hi].
__device__ __forceinline__ void permswap(unsigned& a, unsigned& b) {
  auto r = __builtin_amdgcn_permlane32_swap((int)a, (int)b, false, false);
  a = (unsigned)r[0];
  b = (unsigned)r[1];
}
// Async global->LDS, 16B per lane. Dest is wave-uniform base + lane*16.
__device__ __forceinline__ void gl16(const unsigned short* g, unsigned short* l) {
  __builtin_amdgcn_global_load_lds(
      (const __attribute__((address_space(1))) unsigned int*)g,
      (__attribute__((address_space(3))) unsigned int*)l, 16, 0, 0);
}

// ---------------------------------------------------------------------------
// Software-exact OCP e4m3fn rounding (RTNE via magic-add; matches ml_dtypes
// bit-exact incl. subnormal grid 2^-9 and the 448-saturation region).
// ---------------------------------------------------------------------------
__device__ __forceinline__ float qd_e4m3(float v) {
  float a = fabsf(v);
  unsigned u = __float_as_uint(a);
  int e = (int)(u >> 23) - 127;
  int k = e - 3;
  if (k < -9) k = -9;
  float big = __uint_as_float((unsigned)(k + 150) << 23);  // 2^(k+23)
  float r = (a + big) - big;
  return __builtin_copysignf(r, v);
}

// ---------------------------------------------------------------------------
// Activation quant: per 128-block, emit e4m3 CODES as bf16 (exact) + scale.
// ---------------------------------------------------------------------------
__global__ __launch_bounds__(256) void quant_x(const float* __restrict__ src,
                                               unsigned short* __restrict__ q,
                                               float* __restrict__ s,
                                               int nblk) {
  int gid = blockIdx.x * 256 + threadIdx.x;
  int wid = gid >> 6;
  int lane = gid & 63;
  if (wid >= nblk) return;
  size_t off = (size_t)wid * 128 + lane * 2;
  float2 xv = *reinterpret_cast<const float2*>(src + off);
  float m = fmaxf(fabsf(xv.x), fabsf(xv.y));
#pragma unroll
  for (int d = 32; d > 0; d >>= 1) m = fmaxf(m, __shfl_xor(m, d));
  float scale = fmaxf(m / 448.0f, 1e-12f);
  unsigned short q0 = f2bf(qd_e4m3(xv.x / scale));  // exact: e4m3 ⊂ bf16
  unsigned short q1 = f2bf(qd_e4m3(xv.y / scale));
  *reinterpret_cast<unsigned*>(q + off) = (unsigned)q0 | ((unsigned)q1 << 16);
  if (lane == 0) s[wid] = scale;
}

// ---------------------------------------------------------------------------
// Weight quant + dequant + hi/lo split + TRANSPOSE: W[K,N] -> WTh/WTl[N,K].
// ---------------------------------------------------------------------------
__global__ __launch_bounds__(256) void quant_w_t(const float* __restrict__ W,
                                                 unsigned short* __restrict__ WTh,
                                                 unsigned short* __restrict__ WTl,
                                                 int K, int N) {
  __shared__ __align__(16) unsigned short Ht[128][72];
  __shared__ __align__(16) unsigned short Lt[128][72];
  const int tid = threadIdx.x;
  const int w = tid >> 6, l = tid & 63;
  const int k0 = blockIdx.y * 64, n0 = blockIdx.x * 128;
#pragma unroll 4
  for (int i = 0; i < 16; ++i) {
    int kl = w * 16 + i;
    float2 xv = *reinterpret_cast<const float2*>(&W[(size_t)(k0 + kl) * N + n0 + l * 2]);
    float m = fmaxf(fabsf(xv.x), fabsf(xv.y));
#pragma unroll
    for (int d = 32; d > 0; d >>= 1) m = fmaxf(m, __shfl_xor(m, d));
    float scale = fmaxf(m / 448.0f, 1e-12f);
    float d0 = qd_e4m3(xv.x / scale) * scale;
    float d1 = qd_e4m3(xv.y / scale) * scale;
    unsigned short h0 = f2bf(d0), h1 = f2bf(d1);
    Ht[l * 2][kl] = h0;
    Ht[l * 2 + 1][kl] = h1;
    Lt[l * 2][kl] = f2bf(d0 - bf2f(h0));
    Lt[l * 2 + 1][kl] = f2bf(d1 - bf2f(h1));
  }
  __syncthreads();
  const int arr = tid >> 7, n = tid & 127;
  const unsigned short(*T)[72] = arr ? Lt : Ht;
  unsigned short* dst = (arr ? WTl : WTh) + (size_t)(n0 + n) * K + k0;
#pragma unroll
  for (int j = 0; j < 8; ++j)
    *reinterpret_cast<bfrag*>(dst + j * 8) = *reinterpret_cast<const bfrag*>(&T[n][j * 8]);
}

// ---------------------------------------------------------------------------
// Quantization-aware MFMA GEMM, templated on M-tile: MT = MF*32 rows x 128
// cols. MF=4 (128x128, QKV; round-10 proven) or MF=2 (64x128: out-proj gets
// 512 blocks = 2 blocks/CU instead of 1). global_load_lds w=16 staging with
// both-sides XOR swizzle. Accumulation order per output element unchanged.
// ---------------------------------------------------------------------------
template <int MF, bool SPLIT>
__global__ __launch_bounds__(256, 2) void gemm_q(const unsigned short* __restrict__ Aq,
                                                 const float* __restrict__ As,
                                                 const unsigned short* __restrict__ WTh,
                                                 const unsigned short* __restrict__ WTl,
                                                 const float* __restrict__ bias,
                                                 float* __restrict__ Cf,
                                                 unsigned short* __restrict__ Ch,
                                                 unsigned short* __restrict__ Cl,
                                                 int M, int N, int K) {
  constexpr int MT = MF * 32;
  __shared__ __align__(16) unsigned short Al[MT][64];
  __shared__ __align__(16) unsigned short Bh[128][64];
  __shared__ __align__(16) unsigned short Bl[128][64];
  __shared__ float Ss[MT][8];
  const int tid = threadIdx.x;
  const int w = tid >> 6, l = tid & 63;
  const int lr = l & 15, lg = l >> 4;
  const int nbx = N >> 7;
  const int nwg = nbx * (M / MT);
  const int q8 = nwg >> 3;
  const int swz = ((int)blockIdx.x & 7) * q8 + ((int)blockIdx.x >> 3);
  const int row0 = (swz / nbx) * MT, col0 = (swz % nbx) << 7;
  const int wr = (w >> 1) * (MT / 2), wc = (w & 1) * 64;
  const int xsw = (lr & 7) * 8;        // read-side XOR (short units)

  if (MF == 4) {
    int r = tid >> 1, c0 = (tid & 1) * 4;
    *reinterpret_cast<float4*>(&Ss[r][c0]) =
        *reinterpret_cast<const float4*>(&As[(size_t)(row0 + r) * 8 + c0]);
  } else {
    int r = tid >> 2, c0 = (tid & 3) * 2;
    *reinterpret_cast<float2*>(&Ss[r][c0]) =
        *reinterpret_cast<const float2*>(&As[(size_t)(row0 + r) * 8 + c0]);
  }

  f4 acc[MF][4], seg[MF][4];
#pragma unroll
  for (int i = 0; i < MF; ++i)
#pragma unroll
    for (int j = 0; j < 4; ++j)
#pragma unroll
      for (int c = 0; c < 4; ++c) {
        acc[i][j][c] = 0.f;
        seg[i][j][c] = 0.f;
      }

  const int lrow = l >> 3;             // 0..7
  const int jch = (l & 7) ^ lrow;      // inverse-swizzled source chunk
  const unsigned short* pA = Aq + (size_t)(row0 + w * (MT / 4) + lrow) * K + jch * 8;
  const unsigned short* pH = WTh + (size_t)(col0 + w * 32 + lrow) * K + jch * 8;
  const unsigned short* pL = WTl + (size_t)(col0 + w * 32 + lrow) * K + jch * 8;
  unsigned short* dA = &Al[0][0] + w * (MT / 4) * 64;
  unsigned short* dH = &Bh[0][0] + w * 2048;
  unsigned short* dL = &Bl[0][0] + w * 2048;

  const int niter = K >> 6;
  for (int it = 0; it < niter; ++it) {
    const int k0 = it << 6;
    __syncthreads();
#pragma unroll
    for (int ii = 0; ii < MF; ++ii)
      gl16(pA + (size_t)ii * 8 * K + k0, dA + ii * 512);
#pragma unroll
    for (int ii = 0; ii < 4; ++ii) {
      gl16(pH + (size_t)ii * 8 * K + k0, dH + ii * 512);
      gl16(pL + (size_t)ii * 8 * K + k0, dL + ii * 512);
    }
    __syncthreads();

#pragma unroll
    for (int ks = 0; ks < 2; ++ks) {
      bfrag af[MF];
#pragma unroll
      for (int mf = 0; mf < MF; ++mf)
        af[mf] = *reinterpret_cast<const bfrag*>(
            &Al[0][0] + (wr + mf * 16 + lr) * 64 + ((ks * 32 + lg * 8) ^ xsw));
#pragma unroll
      for (int nf = 0; nf < 4; ++nf) {
        bfrag bh = *reinterpret_cast<const bfrag*>(
            &Bh[0][0] + (wc + nf * 16 + lr) * 64 + ((ks * 32 + lg * 8) ^ xsw));
        bfrag bl = *reinterpret_cast<const bfrag*>(
            &Bl[0][0] + (wc + nf * 16 + lr) * 64 + ((ks * 32 + lg * 8) ^ xsw));
#pragma unroll
        for (int mf = 0; mf < MF; ++mf) {
          seg[mf][nf] = MFMA16(af[mf], bh, seg[mf][nf]);
          seg[mf][nf] = MFMA16(af[mf], bl, seg[mf][nf]);
        }
      }
    }

    if (it & 1) {
      const int kb = it >> 1;
#pragma unroll
      for (int mf = 0; mf < MF; ++mf) {
        float sv[4];
#pragma unroll
        for (int r = 0; r < 4; ++r) sv[r] = Ss[wr + mf * 16 + lg * 4 + r][kb];
#pragma unroll
        for (int nf = 0; nf < 4; ++nf)
#pragma unroll
          for (int r = 0; r < 4; ++r) {
            acc[mf][nf][r] += sv[r] * seg[mf][nf][r];
            seg[mf][nf][r] = 0.f;
          }
      }
    }
  }

#pragma unroll
  for (int mf = 0; mf < MF; ++mf) {
#pragma unroll
    for (int r = 0; r < 4; ++r) {
      const int m = row0 + wr + mf * 16 + lg * 4 + r;
#pragma unroll
      for (int nf = 0; nf < 4; ++nf) {
        const int col = col0 + wc + nf * 16 + lr;
        float o = acc[mf][nf][r] + bias[col];
        if (SPLIT) {
          unsigned short hh = f2bf(o);
          Ch[(size_t)m * N + col] = hh;
          Cl[(size_t)m * N + col] = f2bf(o - bf2f(hh));
        } else {
          Cf[(size_t)m * N + col] = o;
        }
      }
    }
  }
}

// ---------------------------------------------------------------------------
// Swapped-operand 32x32 MFMA flash attention (round-14 version verbatim —
// best measured: 161us, FETCH 24.6MB). XCD-aware 1-D grid: XCD k (= lin%8)
// owns bh in {4k..4k+3} (4 MB KV -> L2-resident).
// ---------------------------------------------------------------------------
__global__ __launch_bounds__(256, 2) void attn_mfma32(const unsigned short* __restrict__ qkvh,
                                                      const unsigned short* __restrict__ qkvl,
                                                      float* __restrict__ out) {
  __shared__ __align__(16) unsigned short Vth[2][64][40];  // V^T: [buf][rho(d)][kpos]
  __shared__ __align__(16) unsigned short Vtl[2][64][40];
  const int tid = threadIdx.x;
  const int w = tid >> 6, l = tid & 63;
  const int q = l & 31;
  const int hi = l >> 5;
  // XCD-aware decode
  const int lin = (int)blockIdx.x;
  const int xcd = lin & 7, j = lin >> 3;
  const int bh = 4 * xcd + (j >> 4);
  const int qt = j & 15;
  const int q0 = qt * 128 + w * 32;
  const int b = bh >> 4, h = bh & 15;
  const size_t bbase = (size_t)b * 2048;
  const size_t hoff = (size_t)h * 64;

  const int rA = (q & 24) | ((q + (q >> 3)) & 7);              // d = q
  const int rB = 32 + ((q & 24) | ((q + 4 + (q >> 3)) & 7));   // d = 32+q

  bfrag qh[4], ql[4];
  {
    const size_t qrow = (bbase + q0 + q) * 3072 + hoff + hi * 8;
#pragma unroll
    for (int f = 0; f < 4; ++f) {
      qh[f] = *reinterpret_cast<const bfrag*>(qkvh + qrow + f * 16);
      ql[f] = *reinterpret_cast<const bfrag*>(qkvl + qrow + f * 16);
    }
  }

  const int skp = tid >> 3;   // 0..31 (kpos)
  const int sc = tid & 7;     // 0..7  (d-chunk of 8)

  const unsigned short* kph = qkvh + (bbase + q) * 3072 + 1024 + hoff + hi * 8;
  const unsigned short* kpl = qkvl + (bbase + q) * 3072 + 1024 + hoff + hi * 8;
  const unsigned short* vph = qkvh + (bbase + skp) * 3072 + 2048 + hoff + sc * 8;
  const unsigned short* vpl = qkvl + (bbase + skp) * 3072 + 2048 + hoff + sc * 8;
  const size_t KSTEP = (size_t)32 * 3072;

  bfrag kh[4], kl[4], svh, svl;

  // ---- prologue: K(0), V(0)->LDS0, QK(0)->sA, K(1) ----
#pragma unroll
  for (int f = 0; f < 4; ++f) {
    kh[f] = *reinterpret_cast<const bfrag*>(kph + f * 16);
    kl[f] = *reinterpret_cast<const bfrag*>(kpl + f * 16);
  }
  svh = *reinterpret_cast<const bfrag*>(vph);
  svl = *reinterpret_cast<const bfrag*>(vpl);
  vph += KSTEP; vpl += KSTEP;
#pragma unroll
  for (int j2 = 0; j2 < 8; ++j2) {  // static element j2 -> row rho(sc*8+j2)
    int row = sc * 8 + ((j2 + sc) & 7);
    Vth[0][row][skp] = (unsigned short)svh[j2];
    Vtl[0][row][skp] = (unsigned short)svl[j2];
  }
  f16v sA, sB;
#pragma unroll
  for (int r = 0; r < 16; ++r) sA[r] = 0.f;
  __builtin_amdgcn_s_setprio(1);
#pragma unroll
  for (int f = 0; f < 4; ++f) sA = MFMA32(kh[f], qh[f], sA);
#pragma unroll
  for (int f = 0; f < 4; ++f) sA = MFMA32(kh[f], ql[f], sA);
#pragma unroll
  for (int f = 0; f < 4; ++f) sA = MFMA32(kl[f], qh[f], sA);
  __builtin_amdgcn_s_setprio(0);
  kph += KSTEP; kpl += KSTEP;
#pragma unroll
  for (int f = 0; f < 4; ++f) {
    kh[f] = *reinterpret_cast<const bfrag*>(kph + f * 16);
    kl[f] = *reinterpret_cast<const bfrag*>(kpl + f * 16);
  }
  __syncthreads();

  f16v oA0, oA1, oB0, oB1;
#pragma unroll
  for (int r = 0; r < 16; ++r) { oA0[r] = 0.f; oA1[r] = 0.f; oB0[r] = 0.f; oB1[r] = 0.f; }
  float m_i = -1e30f, l_i = 0.f;

#define ATTN_ITER(KT, SCUR, SNXT)                                              \
  do {                                                                         \
    const int kt_ = (KT);                                                      \
    const int cur_ = kt_ & 1;                                                  \
    /* 1: issue QK(kt+1) into SNXT (overlaps softmax below) */                 \
    if (kt_ < 63) {                                                            \
      _Pragma("unroll") for (int r = 0; r < 16; ++r) SNXT[r] = 0.f;            \
      __builtin_amdgcn_s_setprio(1);                                           \
      _Pragma("unroll") for (int f = 0; f < 4; ++f)                            \
          SNXT = MFMA32(kh[f], qh[f], SNXT);                                   \
      _Pragma("unroll") for (int f = 0; f < 4; ++f)                            \
          SNXT = MFMA32(kh[f], ql[f], SNXT);                                   \
      _Pragma("unroll") for (int f = 0; f < 4; ++f)                            \
          SNXT = MFMA32(kl[f], qh[f], SNXT);                                   \
      __builtin_amdgcn_s_setprio(0);                                           \
    }                                                                          \
    /* 2: K(kt+2) loads */                                                     \
    if (kt_ < 62) {                                                            \
      kph += KSTEP; kpl += KSTEP;                                              \
      _Pragma("unroll") for (int f = 0; f < 4; ++f) {                          \
        kh[f] = *reinterpret_cast<const bfrag*>(kph + f * 16);                 \
        kl[f] = *reinterpret_cast<const bfrag*>(kpl + f * 16);                 \
      }                                                                        \
    }                                                                          \
    /* 3: softmax on SCUR (VALU — overlaps step-1 MFMAs) */                    \
    float a0 = fmaxf(SCUR[0], SCUR[1]), a1 = fmaxf(SCUR[2], SCUR[3]);          \
    float a2 = fmaxf(SCUR[4], SCUR[5]), a3 = fmaxf(SCUR[6], SCUR[7]);          \
    float a4 = fmaxf(SCUR[8], SCUR[9]), a5 = fmaxf(SCUR[10], SCUR[11]);        \
    float a6 = fmaxf(SCUR[12], SCUR[13]), a7 = fmaxf(SCUR[14], SCUR[15]);      \
    float b0_ = fmaxf(a0, a1), b1_ = fmaxf(a2, a3);                            \
    float b2_ = fmaxf(a4, a5), b3_ = fmaxf(a6, a7);                            \
    float mt = fmaxf(fmaxf(b0_, b1_), fmaxf(b2_, b3_));                        \
    mt = fmaxf(mt, __shfl_xor(mt, 32));                                        \
    mt *= 0.125f;                                                              \
    if (!__all(mt <= m_i)) { /* defer-max: THR=0 is bit-exact */               \
      float mn = fmaxf(m_i, mt);                                               \
      float corr = __expf(m_i - mn);                                           \
      m_i = mn;                                                                \
      l_i *= corr;                                                             \
      _Pragma("unroll") for (int r = 0; r < 16; ++r) {                         \
        oA0[r] *= corr; oA1[r] *= corr; oB0[r] *= corr; oB1[r] *= corr;        \
      }                                                                        \
    }                                                                          \
    float p[16];                                                               \
    _Pragma("unroll") for (int r = 0; r < 16; ++r)                             \
        p[r] = __expf(fmaf(SCUR[r], 0.125f, -m_i));                            \
    float r0_ = (p[0] + p[1]) + (p[2] + p[3]);                                 \
    float r1_ = (p[4] + p[5]) + (p[6] + p[7]);                                 \
    float r2_ = (p[8] + p[9]) + (p[10] + p[11]);                               \
    float r3_ = (p[12] + p[13]) + (p[14] + p[15]);                             \
    float rs = (r0_ + r1_) + (r2_ + r3_);                                      \
    rs += __shfl_xor(rs, 32);                                                  \
    l_i += rs;                                                                 \
    /* 4: issue V(kt+1) load (written to LDS at step 7) */                     \
    if (kt_ < 63) {                                                            \
      svh = *reinterpret_cast<const bfrag*>(vph);                              \
      svl = *reinterpret_cast<const bfrag*>(vpl);                              \
      vph += KSTEP; vpl += KSTEP;                                              \
    }                                                                          \
    /* 5: pack P hi/lo + permlane32_swap frag build */                         \
    unsigned ph_[8], pl_[8];                                                   \
    _Pragma("unroll") for (int i = 0; i < 8; ++i) {                            \
      unsigned hp = cvt_pk_bf16(p[2 * i], p[2 * i + 1]);                       \
      float e0 = p[2 * i] - __uint_as_float(hp << 16);                         \
      float e1 = p[2 * i + 1] - __uint_as_float(hp & 0xffff0000u);             \
      ph_[i] = hp;                                                             \
      pl_[i] = cvt_pk_bf16(e0, e1);                                            \
    }                                                                          \
    permswap(ph_[0], ph_[2]); permswap(ph_[1], ph_[3]);                        \
    permswap(ph_[4], ph_[6]); permswap(ph_[5], ph_[7]);                        \
    permswap(pl_[0], pl_[2]); permswap(pl_[1], pl_[3]);                        \
    permswap(pl_[4], pl_[6]); permswap(pl_[5], pl_[7]);                        \
    union U4 { unsigned u[4]; bfrag f; };                                      \
    U4 f0h, f1h, f0l, f1l;                                                     \
    f0h.u[0] = ph_[0]; f0h.u[1] = ph_[1]; f0h.u[2] = ph_[2]; f0h.u[3] = ph_[3];\
    f1h.u[0] = ph_[4]; f1h.u[1] = ph_[5]; f1h.u[2] = ph_[6]; f1h.u[3] = ph_[7];\
    f0l.u[0] = pl_[0]; f0l.u[1] = pl_[1]; f0l.u[2] = pl_[2]; f0l.u[3] = pl_[3];\
    f1l.u[0] = pl_[4]; f1l.u[1] = pl_[5]; f1l.u[2] = pl_[6]; f1l.u[3] = pl_[7];\
    /* 6: PV(kt) from LDS[cur_], rho rows */                                   \
    __builtin_amdgcn_s_setprio(1);                                             \
    _Pragma("unroll") for (int c = 0; c < 2; ++c) {                            \
      bfrag pF = c ? f1h.f : f0h.f;                                            \
      bfrag pL = c ? f1l.f : f0l.f;                                            \
      bfrag vh0 = *reinterpret_cast<const bfrag*>(&Vth[cur_][rA][c * 16 + hi * 8]); \
      bfrag vl0 = *reinterpret_cast<const bfrag*>(&Vtl[cur_][rA][c * 16 + hi * 8]); \
      bfrag vh1 = *reinterpret_cast<const bfrag*>(&Vth[cur_][rB][c * 16 + hi * 8]); \
      bfrag vl1 = *reinterpret_cast<const bfrag*>(&Vtl[cur_][rB][c * 16 + hi * 8]); \
      oA0 = MFMA32(vh0, pF, oA0);                                              \
      oB0 = MFMA32(vh0, pL, oB0);                                              \
      oB0 = MFMA32(vl0, pF, oB0);                                              \
      oA1 = MFMA32(vh1, pF, oA1);                                              \
      oB1 = MFMA32(vh1, pL, oB1);                                              \
      oB1 = MFMA32(vl1, pF, oB1);                                              \
    }                                                                          \
    __builtin_amdgcn_s_setprio(0);                                             \
    /* 7: write staged V(kt+1) (static element, rho rows), barrier */          \
    if (kt_ < 63) {                                                            \
      _Pragma("unroll") for (int j2 = 0; j2 < 8; ++j2) {                       \
        int row = sc * 8 + ((j2 + sc) & 7);                                    \
        Vth[cur_ ^ 1][row][skp] = (unsigned short)svh[j2];                     \
        Vtl[cur_ ^ 1][row][skp] = (unsigned short)svl[j2];                     \
      }                                                                        \
      __syncthreads();                                                         \
    }                                                                          \
  } while (0)

  for (int kt = 0; kt < 64; kt += 2) {
    ATTN_ITER(kt, sA, sB);
    ATTN_ITER(kt + 1, sB, sA);
  }
#undef ATTN_ITER

  // ---- epilogue: combine chains, normalize, store fp32 [B,S,H*Dh] ----
  float inv = 1.0f / l_i;
  const size_t orow = (bbase + q0 + q) * 1024 + hoff;
#pragma unroll
  for (int dblk = 0; dblk < 2; ++dblk) {
#pragma unroll
    for (int rg = 0; rg < 4; ++rg) {
      float4 o;
      if (dblk == 0) {
        o.x = (oA0[rg * 4 + 0] + oB0[rg * 4 + 0]) * inv;
        o.y = (oA0[rg * 4 + 1] + oB0[rg * 4 + 1]) * inv;
        o.z = (oA0[rg * 4 + 2] + oB0[rg * 4 + 2]) * inv;
        o.w = (oA0[rg * 4 + 3] + oB0[rg * 4 + 3]) * inv;
      } else {
        o.x = (oA1[rg * 4 + 0] + oB1[rg * 4 + 0]) * inv;
        o.y = (oA1[rg * 4 + 1] + oB1[rg * 4 + 1]) * inv;
        o.z = (oA1[rg * 4 + 2] + oB1[rg * 4 + 2]) * inv;
        o.w = (oA1[rg * 4 + 3] + oB1[rg * 4 + 3]) * inv;
      }
      *reinterpret_cast<float4*>(out + orow + dblk * 32 + rg * 8 + hi * 4) = o;
    }
  }
}

// ---------------------------------------------------------------------------
// Workspace layout (72.25 MiB) — unchanged.
// ---------------------------------------------------------------------------
extern "C" void kernel_launch(void* const* d_in, const int* in_sizes, int n_in,
                              void* d_out, int out_size, void* d_ws, size_t ws_size,
                              hipStream_t stream) {
  const float* x     = (const float*)d_in[0];
  const float* W_qkv = (const float*)d_in[1];
  const float* b_qkv = (const float*)d_in[2];
  const float* W_out = (const float*)d_in[3];
  const float* b_out = (const float*)d_in[4];
  float* y = (float*)d_out;

  char* ws = (char*)d_ws;
  const size_t MB = 1u << 20;
  unsigned short* x_q   = (unsigned short*)(ws);
  float*          s_x   = (float*)(ws + 8 * MB);
  unsigned short* wqh   = (unsigned short*)(ws + 8 * MB + 256 * 1024);
  unsigned short* wql   = (unsigned short*)(ws + 14 * MB + 256 * 1024);
  unsigned short* woh   = (unsigned short*)(ws + 20 * MB + 256 * 1024);
  unsigned short* wol   = (unsigned short*)(ws + 22 * MB + 256 * 1024);
  unsigned short* qkvh  = (unsigned short*)(ws + 24 * MB + 256 * 1024);
  unsigned short* qkvl  = (unsigned short*)(ws + 48 * MB + 256 * 1024);

  // 1. quantize activations (codes + scales) and weights (split + transpose)
  quant_x<<<8192, 256, 0, stream>>>(x, x_q, s_x, 32768);
  quant_w_t<<<dim3(24, 16), 256, 0, stream>>>(W_qkv, wqh, wql, 1024, 3072);
  quant_w_t<<<dim3(8, 16), 256, 0, stream>>>(W_out, woh, wol, 1024, 1024);

  // 2. QKV projection (quant-aware MFMA, gload_lds staging) -> split bf16
  gemm_q<4, true><<<768, 256, 0, stream>>>(x_q, s_x, wqh, wql, b_qkv,
                                           nullptr, qkvh, qkvl, 4096, 3072, 1024);

  // 3. pipelined swapped 32x32 MFMA flash attention (XCD-remapped 1-D grid)
  attn_mfma32<<<512, 256, 0, stream>>>(qkvh, qkvl, y);

  // 4. quantize attention output (reuse x_q / s_x buffers)
  quant_x<<<8192, 256, 0, stream>>>(y, x_q, s_x, 32768);

  // 5. output projection: 64x128 tiles -> 512 blocks = 2 blocks/CU
  gemm_q<2, false><<<512, 256, 0, stream>>>(x_q, s_x, woh, wol, b_out,
                                            y, nullptr, nullptr, 4096, 1024, 1024);
}

// Round 18
// 232.738 us; speedup vs baseline: 1.3103x; 1.1698x over previous
//
#include <hip/hip_runtime.h>
#include <cstdint>
#include <cstddef>

typedef __attribute__((ext_vector_type(8))) short bfrag;      // 8x16-bit (4 VGPR)
typedef __attribute__((ext_vector_type(8))) _Float16 hfrag;   // 8 f16 (4 VGPR)
typedef __attribute__((ext_vector_type(2))) __fp16 fp16x2;    // cvt_pkrtz result type
typedef __attribute__((ext_vector_type(4))) float f4;         // 16x16 MFMA C/D
typedef __attribute__((ext_vector_type(16))) float f16v;      // 32x32 MFMA C/D

#define MFMA16(a, b, c) __builtin_amdgcn_mfma_f32_16x16x32_bf16(a, b, c, 0, 0, 0)
#define MFMA32H(a, b, c) __builtin_amdgcn_mfma_f32_32x32x16_f16(a, b, c, 0, 0, 0)

// ---------------------------------------------------------------------------
// fp32 -> bf16 RNE, and hi/lo split helpers (bf16 path: GEMM codes)
// ---------------------------------------------------------------------------
__device__ __forceinline__ unsigned short f2bf(float x) {
  unsigned u = __float_as_uint(x);
  u += 0x7fffu + ((u >> 16) & 1u);
  return (unsigned short)(u >> 16);
}
__device__ __forceinline__ float bf2f(unsigned short h) {
  return __uint_as_float(((unsigned)h) << 16);
}
// fp32 pair -> packed 2x f16 (RTZ; one instruction). lo-residue use is
// rounding-mode-agnostic: the residual compensates whatever hi rounds to.
__device__ __forceinline__ unsigned cvt_pkrtz_u(float a, float b) {
  union { fp16x2 h; unsigned u; } c;
  c.h = __builtin_amdgcn_cvt_pkrtz(a, b);
  return c.u;
}
__device__ __forceinline__ unsigned short f2h_bits(float x) {
  _Float16 h = (_Float16)x;
  union { _Float16 h; unsigned short u; } c;
  c.h = h;
  return c.u;
}
__device__ __forceinline__ float h2f(unsigned short u) {
  union { unsigned short u; _Float16 h; } c;
  c.u = u;
  return (float)c.h;
}
// One-instruction cross-half exchange: a' = [a_lo | b_lo], b' = [a_hi | b_hi].
__device__ __forceinline__ void permswap(unsigned& a, unsigned& b) {
  auto r = __builtin_amdgcn_permlane32_swap((int)a, (int)b, false, false);
  a = (unsigned)r[0];
  b = (unsigned)r[1];
}
// Async global->LDS, 16B per lane. Dest is wave-uniform base + lane*16.
__device__ __forceinline__ void gl16(const unsigned short* g, unsigned short* l) {
  __builtin_amdgcn_global_load_lds(
      (const __attribute__((address_space(1))) unsigned int*)g,
      (__attribute__((address_space(3))) unsigned int*)l, 16, 0, 0);
}

// ---------------------------------------------------------------------------
// Software-exact OCP e4m3fn rounding (RTNE via magic-add; matches ml_dtypes
// bit-exact incl. subnormal grid 2^-9 and the 448-saturation region).
// ---------------------------------------------------------------------------
__device__ __forceinline__ float qd_e4m3(float v) {
  float a = fabsf(v);
  unsigned u = __float_as_uint(a);
  int e = (int)(u >> 23) - 127;
  int k = e - 3;
  if (k < -9) k = -9;
  float big = __uint_as_float((unsigned)(k + 150) << 23);  // 2^(k+23)
  float r = (a + big) - big;
  return __builtin_copysignf(r, v);
}

// ---------------------------------------------------------------------------
// Activation quant: per 128-block, emit e4m3 CODES as bf16 (exact) + scale.
// ---------------------------------------------------------------------------
__global__ __launch_bounds__(256) void quant_x(const float* __restrict__ src,
                                               unsigned short* __restrict__ q,
                                               float* __restrict__ s,
                                               int nblk) {
  int gid = blockIdx.x * 256 + threadIdx.x;
  int wid = gid >> 6;
  int lane = gid & 63;
  if (wid >= nblk) return;
  size_t off = (size_t)wid * 128 + lane * 2;
  float2 xv = *reinterpret_cast<const float2*>(src + off);
  float m = fmaxf(fabsf(xv.x), fabsf(xv.y));
#pragma unroll
  for (int d = 32; d > 0; d >>= 1) m = fmaxf(m, __shfl_xor(m, d));
  float scale = fmaxf(m / 448.0f, 1e-12f);
  unsigned short q0 = f2bf(qd_e4m3(xv.x / scale));  // exact: e4m3 ⊂ bf16
  unsigned short q1 = f2bf(qd_e4m3(xv.y / scale));
  *reinterpret_cast<unsigned*>(q + off) = (unsigned)q0 | ((unsigned)q1 << 16);
  if (lane == 0) s[wid] = scale;
}

// ---------------------------------------------------------------------------
// Weight quant + dequant + hi/lo split + TRANSPOSE: W[K,N] -> WTh/WTl[N,K].
// ---------------------------------------------------------------------------
__global__ __launch_bounds__(256) void quant_w_t(const float* __restrict__ W,
                                                 unsigned short* __restrict__ WTh,
                                                 unsigned short* __restrict__ WTl,
                                                 int K, int N) {
  __shared__ __align__(16) unsigned short Ht[128][72];
  __shared__ __align__(16) unsigned short Lt[128][72];
  const int tid = threadIdx.x;
  const int w = tid >> 6, l = tid & 63;
  const int k0 = blockIdx.y * 64, n0 = blockIdx.x * 128;
#pragma unroll 4
  for (int i = 0; i < 16; ++i) {
    int kl = w * 16 + i;
    float2 xv = *reinterpret_cast<const float2*>(&W[(size_t)(k0 + kl) * N + n0 + l * 2]);
    float m = fmaxf(fabsf(xv.x), fabsf(xv.y));
#pragma unroll
    for (int d = 32; d > 0; d >>= 1) m = fmaxf(m, __shfl_xor(m, d));
    float scale = fmaxf(m / 448.0f, 1e-12f);
    float d0 = qd_e4m3(xv.x / scale) * scale;
    float d1 = qd_e4m3(xv.y / scale) * scale;
    unsigned short h0 = f2bf(d0), h1 = f2bf(d1);
    Ht[l * 2][kl] = h0;
    Ht[l * 2 + 1][kl] = h1;
    Lt[l * 2][kl] = f2bf(d0 - bf2f(h0));
    Lt[l * 2 + 1][kl] = f2bf(d1 - bf2f(h1));
  }
  __syncthreads();
  const int arr = tid >> 7, n = tid & 127;
  const unsigned short(*T)[72] = arr ? Lt : Ht;
  unsigned short* dst = (arr ? WTl : WTh) + (size_t)(n0 + n) * K + k0;
#pragma unroll
  for (int j = 0; j < 8; ++j)
    *reinterpret_cast<bfrag*>(dst + j * 8) = *reinterpret_cast<const bfrag*>(&T[n][j * 8]);
}

// ---------------------------------------------------------------------------
// Quantization-aware MFMA GEMM, templated on M-tile (MF*32 x 128).
// SPLIT=true epilogue now emits FP16 hi/lo (for the 2-pass f16 attention);
// GEMM core unchanged (bf16 codes x bf16-split weights, bit-identical).
// ---------------------------------------------------------------------------
template <int MF, bool SPLIT>
__global__ __launch_bounds__(256, 2) void gemm_q(const unsigned short* __restrict__ Aq,
                                                 const float* __restrict__ As,
                                                 const unsigned short* __restrict__ WTh,
                                                 const unsigned short* __restrict__ WTl,
                                                 const float* __restrict__ bias,
                                                 float* __restrict__ Cf,
                                                 unsigned short* __restrict__ Ch,
                                                 unsigned short* __restrict__ Cl,
                                                 int M, int N, int K) {
  constexpr int MT = MF * 32;
  __shared__ __align__(16) unsigned short Al[MT][64];
  __shared__ __align__(16) unsigned short Bh[128][64];
  __shared__ __align__(16) unsigned short Bl[128][64];
  __shared__ float Ss[MT][8];
  const int tid = threadIdx.x;
  const int w = tid >> 6, l = tid & 63;
  const int lr = l & 15, lg = l >> 4;
  const int nbx = N >> 7;
  const int nwg = nbx * (M / MT);
  const int q8 = nwg >> 3;
  const int swz = ((int)blockIdx.x & 7) * q8 + ((int)blockIdx.x >> 3);
  const int row0 = (swz / nbx) * MT, col0 = (swz % nbx) << 7;
  const int wr = (w >> 1) * (MT / 2), wc = (w & 1) * 64;
  const int xsw = (lr & 7) * 8;        // read-side XOR (short units)

  if (MF == 4) {
    int r = tid >> 1, c0 = (tid & 1) * 4;
    *reinterpret_cast<float4*>(&Ss[r][c0]) =
        *reinterpret_cast<const float4*>(&As[(size_t)(row0 + r) * 8 + c0]);
  } else {
    int r = tid >> 2, c0 = (tid & 3) * 2;
    *reinterpret_cast<float2*>(&Ss[r][c0]) =
        *reinterpret_cast<const float2*>(&As[(size_t)(row0 + r) * 8 + c0]);
  }

  f4 acc[MF][4], seg[MF][4];
#pragma unroll
  for (int i = 0; i < MF; ++i)
#pragma unroll
    for (int j = 0; j < 4; ++j)
#pragma unroll
      for (int c = 0; c < 4; ++c) {
        acc[i][j][c] = 0.f;
        seg[i][j][c] = 0.f;
      }

  const int lrow = l >> 3;             // 0..7
  const int jch = (l & 7) ^ lrow;      // inverse-swizzled source chunk
  const unsigned short* pA = Aq + (size_t)(row0 + w * (MT / 4) + lrow) * K + jch * 8;
  const unsigned short* pH = WTh + (size_t)(col0 + w * 32 + lrow) * K + jch * 8;
  const unsigned short* pL = WTl + (size_t)(col0 + w * 32 + lrow) * K + jch * 8;
  unsigned short* dA = &Al[0][0] + w * (MT / 4) * 64;
  unsigned short* dH = &Bh[0][0] + w * 2048;
  unsigned short* dL = &Bl[0][0] + w * 2048;

  const int niter = K >> 6;
  for (int it = 0; it < niter; ++it) {
    const int k0 = it << 6;
    __syncthreads();
#pragma unroll
    for (int ii = 0; ii < MF; ++ii)
      gl16(pA + (size_t)ii * 8 * K + k0, dA + ii * 512);
#pragma unroll
    for (int ii = 0; ii < 4; ++ii) {
      gl16(pH + (size_t)ii * 8 * K + k0, dH + ii * 512);
      gl16(pL + (size_t)ii * 8 * K + k0, dL + ii * 512);
    }
    __syncthreads();

#pragma unroll
    for (int ks = 0; ks < 2; ++ks) {
      bfrag af[MF];
#pragma unroll
      for (int mf = 0; mf < MF; ++mf)
        af[mf] = *reinterpret_cast<const bfrag*>(
            &Al[0][0] + (wr + mf * 16 + lr) * 64 + ((ks * 32 + lg * 8) ^ xsw));
#pragma unroll
      for (int nf = 0; nf < 4; ++nf) {
        bfrag bh = *reinterpret_cast<const bfrag*>(
            &Bh[0][0] + (wc + nf * 16 + lr) * 64 + ((ks * 32 + lg * 8) ^ xsw));
        bfrag bl = *reinterpret_cast<const bfrag*>(
            &Bl[0][0] + (wc + nf * 16 + lr) * 64 + ((ks * 32 + lg * 8) ^ xsw));
#pragma unroll
        for (int mf = 0; mf < MF; ++mf) {
          seg[mf][nf] = MFMA16(af[mf], bh, seg[mf][nf]);
          seg[mf][nf] = MFMA16(af[mf], bl, seg[mf][nf]);
        }
      }
    }

    if (it & 1) {
      const int kb = it >> 1;
#pragma unroll
      for (int mf = 0; mf < MF; ++mf) {
        float sv[4];
#pragma unroll
        for (int r = 0; r < 4; ++r) sv[r] = Ss[wr + mf * 16 + lg * 4 + r][kb];
#pragma unroll
        for (int nf = 0; nf < 4; ++nf)
#pragma unroll
          for (int r = 0; r < 4; ++r) {
            acc[mf][nf][r] += sv[r] * seg[mf][nf][r];
            seg[mf][nf][r] = 0.f;
          }
      }
    }
  }

#pragma unroll
  for (int mf = 0; mf < MF; ++mf) {
#pragma unroll
    for (int r = 0; r < 4; ++r) {
      const int m = row0 + wr + mf * 16 + lg * 4 + r;
#pragma unroll
      for (int nf = 0; nf < 4; ++nf) {
        const int col = col0 + wc + nf * 16 + lr;
        float o = acc[mf][nf][r] + bias[col];
        if (SPLIT) {
          unsigned short hh = f2h_bits(o);          // fp16 hi
          Ch[(size_t)m * N + col] = hh;
          Cl[(size_t)m * N + col] = f2h_bits(o - h2f(hh));  // fp16 lo
        } else {
          Cf[(size_t)m * N + col] = o;
        }
      }
    }
  }
}

// ---------------------------------------------------------------------------
// Swapped-operand 32x32 MFMA flash attention — FP16-SPLIT 2-PASS (round 17).
// QK: S = Kh·(Qh+Ql)  (omits Kl·Q ~ 2^-12 rel -> ~2.5e-4 on scaled scores;
//     the K-lo stream is never loaded: K traffic halves).
// PV: O = (Vh+Vl)·Ph  (omits Pl·V ~ 2^-11 -> ~2.4e-4 on O; no P-lo pack).
// 16 MFMA/iter (was 24). XCD-aware grid (r14) + rho V-staging + permlane
// pack + QK||softmax pipeline + defer-max(THR=0) retained.
// ---------------------------------------------------------------------------
__global__ __launch_bounds__(256, 2) void attn_mfma32(const unsigned short* __restrict__ qkvh,
                                                      const unsigned short* __restrict__ qkvl,
                                                      float* __restrict__ out) {
  __shared__ __align__(16) unsigned short Vth[2][64][40];  // V^T hi: [buf][rho(d)][kpos]
  __shared__ __align__(16) unsigned short Vtl[2][64][40];  // V^T lo
  const int tid = threadIdx.x;
  const int w = tid >> 6, l = tid & 63;
  const int q = l & 31;
  const int hi = l >> 5;
  // XCD-aware decode: XCD k owns bh in {4k..4k+3} (4 MB KV -> L2-resident)
  const int lin = (int)blockIdx.x;
  const int xcd = lin & 7, j = lin >> 3;
  const int bh = 4 * xcd + (j >> 4);
  const int qt = j & 15;
  const int q0 = qt * 128 + w * 32;
  const int b = bh >> 4, h = bh & 15;
  const size_t bbase = (size_t)b * 2048;
  const size_t hoff = (size_t)h * 64;

  const int rA = (q & 24) | ((q + (q >> 3)) & 7);              // d = q
  const int rB = 32 + ((q & 24) | ((q + 4 + (q >> 3)) & 7));   // d = 32+q

  hfrag qh[4], ql[4];
  {
    const size_t qrow = (bbase + q0 + q) * 3072 + hoff + hi * 8;
#pragma unroll
    for (int f = 0; f < 4; ++f) {
      qh[f] = *reinterpret_cast<const hfrag*>(qkvh + qrow + f * 16);
      ql[f] = *reinterpret_cast<const hfrag*>(qkvl + qrow + f * 16);
    }
  }

  const int skp = tid >> 3;   // 0..31 (kpos)
  const int sc = tid & 7;     // 0..7  (d-chunk of 8)

  const unsigned short* kph = qkvh + (bbase + q) * 3072 + 1024 + hoff + hi * 8;
  const unsigned short* vph = qkvh + (bbase + skp) * 3072 + 2048 + hoff + sc * 8;
  const unsigned short* vpl = qkvl + (bbase + skp) * 3072 + 2048 + hoff + sc * 8;
  const size_t KSTEP = (size_t)32 * 3072;

  hfrag kh[4];
  bfrag svh, svl;

  // ---- prologue: K(0), V(0)->LDS0, QK(0)->sA, K(1) ----
#pragma unroll
  for (int f = 0; f < 4; ++f)
    kh[f] = *reinterpret_cast<const hfrag*>(kph + f * 16);
  svh = *reinterpret_cast<const bfrag*>(vph);
  svl = *reinterpret_cast<const bfrag*>(vpl);
  vph += KSTEP; vpl += KSTEP;
#pragma unroll
  for (int j2 = 0; j2 < 8; ++j2) {  // static element j2 -> row rho(sc*8+j2)
    int row = sc * 8 + ((j2 + sc) & 7);
    Vth[0][row][skp] = (unsigned short)svh[j2];
    Vtl[0][row][skp] = (unsigned short)svl[j2];
  }
  f16v sA, sB;
#pragma unroll
  for (int r = 0; r < 16; ++r) sA[r] = 0.f;
  __builtin_amdgcn_s_setprio(1);
#pragma unroll
  for (int f = 0; f < 4; ++f) sA = MFMA32H(kh[f], qh[f], sA);
#pragma unroll
  for (int f = 0; f < 4; ++f) sA = MFMA32H(kh[f], ql[f], sA);
  __builtin_amdgcn_s_setprio(0);
  kph += KSTEP;
#pragma unroll
  for (int f = 0; f < 4; ++f)
    kh[f] = *reinterpret_cast<const hfrag*>(kph + f * 16);
  __syncthreads();

  f16v oA0, oA1, oB0, oB1;
#pragma unroll
  for (int r = 0; r < 16; ++r) { oA0[r] = 0.f; oA1[r] = 0.f; oB0[r] = 0.f; oB1[r] = 0.f; }
  float m_i = -1e30f, l_i = 0.f;

#define ATTN_ITER(KT, SCUR, SNXT)                                              \
  do {                                                                         \
    const int kt_ = (KT);                                                      \
    const int cur_ = kt_ & 1;                                                  \
    /* 1: issue QK(kt+1) into SNXT (2-pass f16; overlaps softmax below) */     \
    if (kt_ < 63) {                                                            \
      _Pragma("unroll") for (int r = 0; r < 16; ++r) SNXT[r] = 0.f;            \
      __builtin_amdgcn_s_setprio(1);                                           \
      _Pragma("unroll") for (int f = 0; f < 4; ++f)                            \
          SNXT = MFMA32H(kh[f], qh[f], SNXT);                                  \
      _Pragma("unroll") for (int f = 0; f < 4; ++f)                            \
          SNXT = MFMA32H(kh[f], ql[f], SNXT);                                  \
      __builtin_amdgcn_s_setprio(0);                                           \
    }                                                                          \
    /* 2: K(kt+2) loads (hi stream only) */                                    \
    if (kt_ < 62) {                                                            \
      kph += KSTEP;                                                            \
      _Pragma("unroll") for (int f = 0; f < 4; ++f)                            \
          kh[f] = *reinterpret_cast<const hfrag*>(kph + f * 16);               \
    }                                                                          \
    /* 3: softmax on SCUR (VALU — overlaps step-1 MFMAs) */                    \
    float a0 = fmaxf(SCUR[0], SCUR[1]), a1 = fmaxf(SCUR[2], SCUR[3]);          \
    float a2 = fmaxf(SCUR[4], SCUR[5]), a3 = fmaxf(SCUR[6], SCUR[7]);          \
    float a4 = fmaxf(SCUR[8], SCUR[9]), a5 = fmaxf(SCUR[10], SCUR[11]);        \
    float a6 = fmaxf(SCUR[12], SCUR[13]), a7 = fmaxf(SCUR[14], SCUR[15]);      \
    float b0_ = fmaxf(a0, a1), b1_ = fmaxf(a2, a3);                            \
    float b2_ = fmaxf(a4, a5), b3_ = fmaxf(a6, a7);                            \
    float mt = fmaxf(fmaxf(b0_, b1_), fmaxf(b2_, b3_));                        \
    mt = fmaxf(mt, __shfl_xor(mt, 32));                                        \
    mt *= 0.125f;                                                              \
    if (!__all(mt <= m_i)) { /* defer-max: THR=0 is bit-exact */               \
      float mn = fmaxf(m_i, mt);                                               \
      float corr = __expf(m_i - mn);                                           \
      m_i = mn;                                                                \
      l_i *= corr;                                                             \
      _Pragma("unroll") for (int r = 0; r < 16; ++r) {                         \
        oA0[r] *= corr; oA1[r] *= corr; oB0[r] *= corr; oB1[r] *= corr;        \
      }                                                                        \
    }                                                                          \
    float p[16];                                                               \
    _Pragma("unroll") for (int r = 0; r < 16; ++r)                             \
        p[r] = __expf(fmaf(SCUR[r], 0.125f, -m_i));                            \
    float r0_ = (p[0] + p[1]) + (p[2] + p[3]);                                 \
    float r1_ = (p[4] + p[5]) + (p[6] + p[7]);                                 \
    float r2_ = (p[8] + p[9]) + (p[10] + p[11]);                               \
    float r3_ = (p[12] + p[13]) + (p[14] + p[15]);                             \
    float rs = (r0_ + r1_) + (r2_ + r3_);                                      \
    rs += __shfl_xor(rs, 32);                                                  \
    l_i += rs;                                                                 \
    /* 4: issue V(kt+1) load (written to LDS at step 7) */                     \
    if (kt_ < 63) {                                                            \
      svh = *reinterpret_cast<const bfrag*>(vph);                              \
      svl = *reinterpret_cast<const bfrag*>(vpl);                              \
      vph += KSTEP; vpl += KSTEP;                                              \
    }                                                                          \
    /* 5: pack P hi (fp16, RTZ) + permlane32_swap frag build — no lo pack */   \
    unsigned ph_[8];                                                           \
    _Pragma("unroll") for (int i = 0; i < 8; ++i)                              \
        ph_[i] = cvt_pkrtz_u(p[2 * i], p[2 * i + 1]);                          \
    permswap(ph_[0], ph_[2]); permswap(ph_[1], ph_[3]);                        \
    permswap(ph_[4], ph_[6]); permswap(ph_[5], ph_[7]);                        \
    union U4 { unsigned u[4]; hfrag f; };                                      \
    U4 f0h, f1h;                                                               \
    f0h.u[0] = ph_[0]; f0h.u[1] = ph_[1]; f0h.u[2] = ph_[2]; f0h.u[3] = ph_[3];\
    f1h.u[0] = ph_[4]; f1h.u[1] = ph_[5]; f1h.u[2] = ph_[6]; f1h.u[3] = ph_[7];\
    /* 6: PV(kt) from LDS[cur_], rho rows; 2-pass: (Vh+Vl)·Ph */               \
    __builtin_amdgcn_s_setprio(1);                                             \
    _Pragma("unroll") for (int c = 0; c < 2; ++c) {                            \
      hfrag pF = c ? f1h.f : f0h.f;                                            \
      hfrag vh0 = *reinterpret_cast<const hfrag*>(&Vth[cur_][rA][c * 16 + hi * 8]); \
      hfrag vl0 = *reinterpret_cast<const hfrag*>(&Vtl[cur_][rA][c * 16 + hi * 8]); \
      hfrag vh1 = *reinterpret_cast<const hfrag*>(&Vth[cur_][rB][c * 16 + hi * 8]); \
      hfrag vl1 = *reinterpret_cast<const hfrag*>(&Vtl[cur_][rB][c * 16 + hi * 8]); \
      oA0 = MFMA32H(vh0, pF, oA0);                                             \
      oB0 = MFMA32H(vl0, pF, oB0);                                             \
      oA1 = MFMA32H(vh1, pF, oA1);                                             \
      oB1 = MFMA32H(vl1, pF, oB1);                                             \
    }                                                                          \
    __builtin_amdgcn_s_setprio(0);                                             \
    /* 7: write staged V(kt+1) (static element, rho rows), barrier */          \
    if (kt_ < 63) {                                                            \
      _Pragma("unroll") for (int j2 = 0; j2 < 8; ++j2) {                       \
        int row = sc * 8 + ((j2 + sc) & 7);                                    \
        Vth[cur_ ^ 1][row][skp] = (unsigned short)svh[j2];                     \
        Vtl[cur_ ^ 1][row][skp] = (unsigned short)svl[j2];                     \
      }                                                                        \
      __syncthreads();                                                         \
    }                                                                          \
  } while (0)

  for (int kt = 0; kt < 64; kt += 2) {
    ATTN_ITER(kt, sA, sB);
    ATTN_ITER(kt + 1, sB, sA);
  }
#undef ATTN_ITER

  // ---- epilogue: combine chains, normalize, store fp32 [B,S,H*Dh] ----
  float inv = 1.0f / l_i;
  const size_t orow = (bbase + q0 + q) * 1024 + hoff;
#pragma unroll
  for (int dblk = 0; dblk < 2; ++dblk) {
#pragma unroll
    for (int rg = 0; rg < 4; ++rg) {
      float4 o;
      if (dblk == 0) {
        o.x = (oA0[rg * 4 + 0] + oB0[rg * 4 + 0]) * inv;
        o.y = (oA0[rg * 4 + 1] + oB0[rg * 4 + 1]) * inv;
        o.z = (oA0[rg * 4 + 2] + oB0[rg * 4 + 2]) * inv;
        o.w = (oA0[rg * 4 + 3] + oB0[rg * 4 + 3]) * inv;
      } else {
        o.x = (oA1[rg * 4 + 0] + oB1[rg * 4 + 0]) * inv;
        o.y = (oA1[rg * 4 + 1] + oB1[rg * 4 + 1]) * inv;
        o.z = (oA1[rg * 4 + 2] + oB1[rg * 4 + 2]) * inv;
        o.w = (oA1[rg * 4 + 3] + oB1[rg * 4 + 3]) * inv;
      }
      *reinterpret_cast<float4*>(out + orow + dblk * 32 + rg * 8 + hi * 4) = o;
    }
  }
}

// ---------------------------------------------------------------------------
// Workspace layout (72.25 MiB) — unchanged (qkvh/qkvl now hold fp16 hi/lo).
// ---------------------------------------------------------------------------
extern "C" void kernel_launch(void* const* d_in, const int* in_sizes, int n_in,
                              void* d_out, int out_size, void* d_ws, size_t ws_size,
                              hipStream_t stream) {
  const float* x     = (const float*)d_in[0];
  const float* W_qkv = (const float*)d_in[1];
  const float* b_qkv = (const float*)d_in[2];
  const float* W_out = (const float*)d_in[3];
  const float* b_out = (const float*)d_in[4];
  float* y = (float*)d_out;

  char* ws = (char*)d_ws;
  const size_t MB = 1u << 20;
  unsigned short* x_q   = (unsigned short*)(ws);
  float*          s_x   = (float*)(ws + 8 * MB);
  unsigned short* wqh   = (unsigned short*)(ws + 8 * MB + 256 * 1024);
  unsigned short* wql   = (unsigned short*)(ws + 14 * MB + 256 * 1024);
  unsigned short* woh   = (unsigned short*)(ws + 20 * MB + 256 * 1024);
  unsigned short* wol   = (unsigned short*)(ws + 22 * MB + 256 * 1024);
  unsigned short* qkvh  = (unsigned short*)(ws + 24 * MB + 256 * 1024);
  unsigned short* qkvl  = (unsigned short*)(ws + 48 * MB + 256 * 1024);

  // 1. quantize activations (codes + scales) and weights (split + transpose)
  quant_x<<<8192, 256, 0, stream>>>(x, x_q, s_x, 32768);
  quant_w_t<<<dim3(24, 16), 256, 0, stream>>>(W_qkv, wqh, wql, 1024, 3072);
  quant_w_t<<<dim3(8, 16), 256, 0, stream>>>(W_out, woh, wol, 1024, 1024);

  // 2. QKV projection -> FP16 hi/lo split (for the 2-pass f16 attention)
  gemm_q<4, true><<<768, 256, 0, stream>>>(x_q, s_x, wqh, wql, b_qkv,
                                           nullptr, qkvh, qkvl, 4096, 3072, 1024);

  // 3. fp16-split 2-pass flash attention (XCD-remapped 1-D grid)
  attn_mfma32<<<512, 256, 0, stream>>>(qkvh, qkvl, y);

  // 4. quantize attention output (reuse x_q / s_x buffers)
  quant_x<<<8192, 256, 0, stream>>>(y, x_q, s_x, 32768);

  // 5. output projection: 64x128 tiles -> 512 blocks = 2 blocks/CU
  gemm_q<2, false><<<512, 256, 0, stream>>>(x_q, s_x, woh, wol, b_out,
                                            y, nullptr, nullptr, 4096, 1024, 1024);
}

// Round 19
// 203.658 us; speedup vs baseline: 1.4974x; 1.1428x over previous
//
#include <hip/hip_runtime.h>
#include <cstdint>
#include <cstddef>

typedef __attribute__((ext_vector_type(8))) short bfrag;      // 8x16-bit (4 VGPR)
typedef __attribute__((ext_vector_type(8))) _Float16 hfrag;   // 8 f16 (4 VGPR)
typedef __attribute__((ext_vector_type(2))) __fp16 fp16x2;    // cvt_pkrtz result type
typedef __attribute__((ext_vector_type(4))) float f4;         // 16x16 MFMA C/D
typedef __attribute__((ext_vector_type(16))) float f16v;      // 32x32 MFMA C/D

#define MFMA16H(a, b, c) __builtin_amdgcn_mfma_f32_16x16x32_f16(a, b, c, 0, 0, 0)
#define MFMA32H(a, b, c) __builtin_amdgcn_mfma_f32_32x32x16_f16(a, b, c, 0, 0, 0)

// ---------------------------------------------------------------------------
// fp16 helpers. fp32 pair -> packed 2x f16 (RTZ; one instruction); lo-residue
// use is rounding-mode-agnostic (the residual compensates hi's rounding).
// ---------------------------------------------------------------------------
__device__ __forceinline__ unsigned cvt_pkrtz_u(float a, float b) {
  union { fp16x2 h; unsigned u; } c;
  c.h = __builtin_amdgcn_cvt_pkrtz(a, b);
  return c.u;
}
__device__ __forceinline__ unsigned short f2h_bits(float x) {  // RNE
  _Float16 h = (_Float16)x;
  union { _Float16 h; unsigned short u; } c;
  c.h = h;
  return c.u;
}
__device__ __forceinline__ float h2f(unsigned short u) {
  union { unsigned short u; _Float16 h; } c;
  c.u = u;
  return (float)c.h;
}
// One-instruction cross-half exchange: a' = [a_lo | b_lo], b' = [a_hi | b_hi].
__device__ __forceinline__ void permswap(unsigned& a, unsigned& b) {
  auto r = __builtin_amdgcn_permlane32_swap((int)a, (int)b, false, false);
  a = (unsigned)r[0];
  b = (unsigned)r[1];
}
// Async global->LDS, 16B per lane. Dest is wave-uniform base + lane*16.
__device__ __forceinline__ void gl16(const unsigned short* g, unsigned short* l) {
  __builtin_amdgcn_global_load_lds(
      (const __attribute__((address_space(1))) unsigned int*)g,
      (__attribute__((address_space(3))) unsigned int*)l, 16, 0, 0);
}

// ---------------------------------------------------------------------------
// Software-exact OCP e4m3fn rounding (RTNE via magic-add; matches ml_dtypes
// bit-exact incl. subnormal grid 2^-9 and the 448-saturation region).
// ---------------------------------------------------------------------------
__device__ __forceinline__ float qd_e4m3(float v) {
  float a = fabsf(v);
  unsigned u = __float_as_uint(a);
  int e = (int)(u >> 23) - 127;
  int k = e - 3;
  if (k < -9) k = -9;
  float big = __uint_as_float((unsigned)(k + 150) << 23);  // 2^(k+23)
  float r = (a + big) - big;
  return __builtin_copysignf(r, v);
}

// ---------------------------------------------------------------------------
// Activation quant: per 128-block, emit e4m3 CODES as FP16 (exact: 4
// significant bits and range [2^-9,448] are fp16-representable) + scale.
// ---------------------------------------------------------------------------
__global__ __launch_bounds__(256) void quant_x(const float* __restrict__ src,
                                               unsigned short* __restrict__ q,
                                               float* __restrict__ s,
                                               int nblk) {
  int gid = blockIdx.x * 256 + threadIdx.x;
  int wid = gid >> 6;
  int lane = gid & 63;
  if (wid >= nblk) return;
  size_t off = (size_t)wid * 128 + lane * 2;
  float2 xv = *reinterpret_cast<const float2*>(src + off);
  float m = fmaxf(fabsf(xv.x), fabsf(xv.y));
#pragma unroll
  for (int d = 32; d > 0; d >>= 1) m = fmaxf(m, __shfl_xor(m, d));
  float scale = fmaxf(m / 448.0f, 1e-12f);
  unsigned short q0 = f2h_bits(qd_e4m3(xv.x / scale));  // exact: e4m3 ⊂ fp16
  unsigned short q1 = f2h_bits(qd_e4m3(xv.y / scale));
  *reinterpret_cast<unsigned*>(q + off) = (unsigned)q0 | ((unsigned)q1 << 16);
  if (lane == 0) s[wid] = scale;
}

// ---------------------------------------------------------------------------
// Weight quant + dequant -> FP16 (RNE, rel err <= 2^-12) + TRANSPOSE:
// W[K,N] -> WT[N,K]. Single stream (no lo residual).
// ---------------------------------------------------------------------------
__global__ __launch_bounds__(256) void quant_w_t(const float* __restrict__ W,
                                                 unsigned short* __restrict__ WT,
                                                 int K, int N) {
  __shared__ __align__(16) unsigned short Ht[128][72];
  const int tid = threadIdx.x;
  const int w = tid >> 6, l = tid & 63;
  const int k0 = blockIdx.y * 64, n0 = blockIdx.x * 128;
#pragma unroll 4
  for (int i = 0; i < 16; ++i) {
    int kl = w * 16 + i;
    float2 xv = *reinterpret_cast<const float2*>(&W[(size_t)(k0 + kl) * N + n0 + l * 2]);
    float m = fmaxf(fabsf(xv.x), fabsf(xv.y));
#pragma unroll
    for (int d = 32; d > 0; d >>= 1) m = fmaxf(m, __shfl_xor(m, d));
    float scale = fmaxf(m / 448.0f, 1e-12f);
    Ht[l * 2][kl]     = f2h_bits(qd_e4m3(xv.x / scale) * scale);
    Ht[l * 2 + 1][kl] = f2h_bits(qd_e4m3(xv.y / scale) * scale);
  }
  __syncthreads();
  const int n = tid & 127, hs = tid >> 7;   // thread -> (n-row, k-half)
  unsigned short* dst = WT + (size_t)(n0 + n) * K + k0 + hs * 32;
#pragma unroll
  for (int j = 0; j < 4; ++j)
    *reinterpret_cast<bfrag*>(dst + j * 8) =
        *reinterpret_cast<const bfrag*>(&Ht[n][hs * 32 + j * 8]);
}

// ---------------------------------------------------------------------------
// Quantization-aware MFMA GEMM, FP16 1-PASS (round 19): A = e4m3 codes in
// fp16 (EXACT), B = fp16 W_dq (2^-12 rel). 8 MFMA + (MF+4) gl16 per iter
// (was 16 + MF+8). Per-k-block scale fold unchanged. SPLIT=true epilogue
// emits fp16 hi/lo of y for the 2-pass f16 attention.
// ---------------------------------------------------------------------------
template <int MF, bool SPLIT>
__global__ __launch_bounds__(256, 2) void gemm_q(const unsigned short* __restrict__ Aq,
                                                 const float* __restrict__ As,
                                                 const unsigned short* __restrict__ WT,
                                                 const float* __restrict__ bias,
                                                 float* __restrict__ Cf,
                                                 unsigned short* __restrict__ Ch,
                                                 unsigned short* __restrict__ Cl,
                                                 int M, int N, int K) {
  constexpr int MT = MF * 32;
  __shared__ __align__(16) unsigned short Al[MT][64];
  __shared__ __align__(16) unsigned short Bh[128][64];
  __shared__ float Ss[MT][8];
  const int tid = threadIdx.x;
  const int w = tid >> 6, l = tid & 63;
  const int lr = l & 15, lg = l >> 4;
  const int nbx = N >> 7;
  const int nwg = nbx * (M / MT);
  const int q8 = nwg >> 3;
  const int swz = ((int)blockIdx.x & 7) * q8 + ((int)blockIdx.x >> 3);
  const int row0 = (swz / nbx) * MT, col0 = (swz % nbx) << 7;
  const int wr = (w >> 1) * (MT / 2), wc = (w & 1) * 64;
  const int xsw = (lr & 7) * 8;        // read-side XOR (short units)

  if (MF == 4) {
    int r = tid >> 1, c0 = (tid & 1) * 4;
    *reinterpret_cast<float4*>(&Ss[r][c0]) =
        *reinterpret_cast<const float4*>(&As[(size_t)(row0 + r) * 8 + c0]);
  } else {
    int r = tid >> 2, c0 = (tid & 3) * 2;
    *reinterpret_cast<float2*>(&Ss[r][c0]) =
        *reinterpret_cast<const float2*>(&As[(size_t)(row0 + r) * 8 + c0]);
  }

  f4 acc[MF][4], seg[MF][4];
#pragma unroll
  for (int i = 0; i < MF; ++i)
#pragma unroll
    for (int j = 0; j < 4; ++j)
#pragma unroll
      for (int c = 0; c < 4; ++c) {
        acc[i][j][c] = 0.f;
        seg[i][j][c] = 0.f;
      }

  const int lrow = l >> 3;             // 0..7
  const int jch = (l & 7) ^ lrow;      // inverse-swizzled source chunk
  const unsigned short* pA = Aq + (size_t)(row0 + w * (MT / 4) + lrow) * K + jch * 8;
  const unsigned short* pH = WT + (size_t)(col0 + w * 32 + lrow) * K + jch * 8;
  unsigned short* dA = &Al[0][0] + w * (MT / 4) * 64;
  unsigned short* dH = &Bh[0][0] + w * 2048;

  const int niter = K >> 6;
  for (int it = 0; it < niter; ++it) {
    const int k0 = it << 6;
    __syncthreads();
#pragma unroll
    for (int ii = 0; ii < MF; ++ii)
      gl16(pA + (size_t)ii * 8 * K + k0, dA + ii * 512);
#pragma unroll
    for (int ii = 0; ii < 4; ++ii)
      gl16(pH + (size_t)ii * 8 * K + k0, dH + ii * 512);
    __syncthreads();

#pragma unroll
    for (int ks = 0; ks < 2; ++ks) {
      hfrag af[MF];
#pragma unroll
      for (int mf = 0; mf < MF; ++mf)
        af[mf] = *reinterpret_cast<const hfrag*>(
            &Al[0][0] + (wr + mf * 16 + lr) * 64 + ((ks * 32 + lg * 8) ^ xsw));
#pragma unroll
      for (int nf = 0; nf < 4; ++nf) {
        hfrag bh = *reinterpret_cast<const hfrag*>(
            &Bh[0][0] + (wc + nf * 16 + lr) * 64 + ((ks * 32 + lg * 8) ^ xsw));
#pragma unroll
        for (int mf = 0; mf < MF; ++mf)
          seg[mf][nf] = MFMA16H(af[mf], bh, seg[mf][nf]);
      }
    }

    if (it & 1) {
      const int kb = it >> 1;
#pragma unroll
      for (int mf = 0; mf < MF; ++mf) {
        float sv[4];
#pragma unroll
        for (int r = 0; r < 4; ++r) sv[r] = Ss[wr + mf * 16 + lg * 4 + r][kb];
#pragma unroll
        for (int nf = 0; nf < 4; ++nf)
#pragma unroll
          for (int r = 0; r < 4; ++r) {
            acc[mf][nf][r] += sv[r] * seg[mf][nf][r];
            seg[mf][nf][r] = 0.f;
          }
      }
    }
  }

#pragma unroll
  for (int mf = 0; mf < MF; ++mf) {
#pragma unroll
    for (int r = 0; r < 4; ++r) {
      const int m = row0 + wr + mf * 16 + lg * 4 + r;
#pragma unroll
      for (int nf = 0; nf < 4; ++nf) {
        const int col = col0 + wc + nf * 16 + lr;
        float o = acc[mf][nf][r] + bias[col];
        if (SPLIT) {
          unsigned short hh = f2h_bits(o);                  // fp16 hi
          Ch[(size_t)m * N + col] = hh;
          Cl[(size_t)m * N + col] = f2h_bits(o - h2f(hh));  // fp16 lo
        } else {
          Cf[(size_t)m * N + col] = o;
        }
      }
    }
  }
}

// ---------------------------------------------------------------------------
// Swapped-operand 32x32 MFMA flash attention — FP16-SPLIT 2-PASS (round-18
// version verbatim, measured 110us). XCD-aware grid + rho V-staging +
// permlane pack + QK||softmax pipeline + defer-max(THR=0).
// ---------------------------------------------------------------------------
__global__ __launch_bounds__(256, 2) void attn_mfma32(const unsigned short* __restrict__ qkvh,
                                                      const unsigned short* __restrict__ qkvl,
                                                      float* __restrict__ out) {
  __shared__ __align__(16) unsigned short Vth[2][64][40];  // V^T hi: [buf][rho(d)][kpos]
  __shared__ __align__(16) unsigned short Vtl[2][64][40];  // V^T lo
  const int tid = threadIdx.x;
  const int w = tid >> 6, l = tid & 63;
  const int q = l & 31;
  const int hi = l >> 5;
  // XCD-aware decode: XCD k owns bh in {4k..4k+3} (4 MB KV -> L2-resident)
  const int lin = (int)blockIdx.x;
  const int xcd = lin & 7, j = lin >> 3;
  const int bh = 4 * xcd + (j >> 4);
  const int qt = j & 15;
  const int q0 = qt * 128 + w * 32;
  const int b = bh >> 4, h = bh & 15;
  const size_t bbase = (size_t)b * 2048;
  const size_t hoff = (size_t)h * 64;

  const int rA = (q & 24) | ((q + (q >> 3)) & 7);              // d = q
  const int rB = 32 + ((q & 24) | ((q + 4 + (q >> 3)) & 7));   // d = 32+q

  hfrag qh[4], ql[4];
  {
    const size_t qrow = (bbase + q0 + q) * 3072 + hoff + hi * 8;
#pragma unroll
    for (int f = 0; f < 4; ++f) {
      qh[f] = *reinterpret_cast<const hfrag*>(qkvh + qrow + f * 16);
      ql[f] = *reinterpret_cast<const hfrag*>(qkvl + qrow + f * 16);
    }
  }

  const int skp = tid >> 3;   // 0..31 (kpos)
  const int sc = tid & 7;     // 0..7  (d-chunk of 8)

  const unsigned short* kph = qkvh + (bbase + q) * 3072 + 1024 + hoff + hi * 8;
  const unsigned short* vph = qkvh + (bbase + skp) * 3072 + 2048 + hoff + sc * 8;
  const unsigned short* vpl = qkvl + (bbase + skp) * 3072 + 2048 + hoff + sc * 8;
  const size_t KSTEP = (size_t)32 * 3072;

  hfrag kh[4];
  bfrag svh, svl;

  // ---- prologue: K(0), V(0)->LDS0, QK(0)->sA, K(1) ----
#pragma unroll
  for (int f = 0; f < 4; ++f)
    kh[f] = *reinterpret_cast<const hfrag*>(kph + f * 16);
  svh = *reinterpret_cast<const bfrag*>(vph);
  svl = *reinterpret_cast<const bfrag*>(vpl);
  vph += KSTEP; vpl += KSTEP;
#pragma unroll
  for (int j2 = 0; j2 < 8; ++j2) {  // static element j2 -> row rho(sc*8+j2)
    int row = sc * 8 + ((j2 + sc) & 7);
    Vth[0][row][skp] = (unsigned short)svh[j2];
    Vtl[0][row][skp] = (unsigned short)svl[j2];
  }
  f16v sA, sB;
#pragma unroll
  for (int r = 0; r < 16; ++r) sA[r] = 0.f;
  __builtin_amdgcn_s_setprio(1);
#pragma unroll
  for (int f = 0; f < 4; ++f) sA = MFMA32H(kh[f], qh[f], sA);
#pragma unroll
  for (int f = 0; f < 4; ++f) sA = MFMA32H(kh[f], ql[f], sA);
  __builtin_amdgcn_s_setprio(0);
  kph += KSTEP;
#pragma unroll
  for (int f = 0; f < 4; ++f)
    kh[f] = *reinterpret_cast<const hfrag*>(kph + f * 16);
  __syncthreads();

  f16v oA0, oA1, oB0, oB1;
#pragma unroll
  for (int r = 0; r < 16; ++r) { oA0[r] = 0.f; oA1[r] = 0.f; oB0[r] = 0.f; oB1[r] = 0.f; }
  float m_i = -1e30f, l_i = 0.f;

#define ATTN_ITER(KT, SCUR, SNXT)                                              \
  do {                                                                         \
    const int kt_ = (KT);                                                      \
    const int cur_ = kt_ & 1;                                                  \
    /* 1: issue QK(kt+1) into SNXT (2-pass f16; overlaps softmax below) */     \
    if (kt_ < 63) {                                                            \
      _Pragma("unroll") for (int r = 0; r < 16; ++r) SNXT[r] = 0.f;            \
      __builtin_amdgcn_s_setprio(1);                                           \
      _Pragma("unroll") for (int f = 0; f < 4; ++f)                            \
          SNXT = MFMA32H(kh[f], qh[f], SNXT);                                  \
      _Pragma("unroll") for (int f = 0; f < 4; ++f)                            \
          SNXT = MFMA32H(kh[f], ql[f], SNXT);                                  \
      __builtin_amdgcn_s_setprio(0);                                           \
    }                                                                          \
    /* 2: K(kt+2) loads (hi stream only) */                                    \
    if (kt_ < 62) {                                                            \
      kph += KSTEP;                                                            \
      _Pragma("unroll") for (int f = 0; f < 4; ++f)                            \
          kh[f] = *reinterpret_cast<const hfrag*>(kph + f * 16);               \
    }                                                                          \
    /* 3: softmax on SCUR (VALU — overlaps step-1 MFMAs) */                    \
    float a0 = fmaxf(SCUR[0], SCUR[1]), a1 = fmaxf(SCUR[2], SCUR[3]);          \
    float a2 = fmaxf(SCUR[4], SCUR[5]), a3 = fmaxf(SCUR[6], SCUR[7]);          \
    float a4 = fmaxf(SCUR[8], SCUR[9]), a5 = fmaxf(SCUR[10], SCUR[11]);        \
    float a6 = fmaxf(SCUR[12], SCUR[13]), a7 = fmaxf(SCUR[14], SCUR[15]);      \
    float b0_ = fmaxf(a0, a1), b1_ = fmaxf(a2, a3);                            \
    float b2_ = fmaxf(a4, a5), b3_ = fmaxf(a6, a7);                            \
    float mt = fmaxf(fmaxf(b0_, b1_), fmaxf(b2_, b3_));                        \
    mt = fmaxf(mt, __shfl_xor(mt, 32));                                        \
    mt *= 0.125f;                                                              \
    if (!__all(mt <= m_i)) { /* defer-max: THR=0 is bit-exact */               \
      float mn = fmaxf(m_i, mt);                                               \
      float corr = __expf(m_i - mn);                                           \
      m_i = mn;                                                                \
      l_i *= corr;                                                             \
      _Pragma("unroll") for (int r = 0; r < 16; ++r) {                         \
        oA0[r] *= corr; oA1[r] *= corr; oB0[r] *= corr; oB1[r] *= corr;        \
      }                                                                        \
    }                                                                          \
    float p[16];                                                               \
    _Pragma("unroll") for (int r = 0; r < 16; ++r)                             \
        p[r] = __expf(fmaf(SCUR[r], 0.125f, -m_i));                            \
    float r0_ = (p[0] + p[1]) + (p[2] + p[3]);                                 \
    float r1_ = (p[4] + p[5]) + (p[6] + p[7]);                                 \
    float r2_ = (p[8] + p[9]) + (p[10] + p[11]);                               \
    float r3_ = (p[12] + p[13]) + (p[14] + p[15]);                             \
    float rs = (r0_ + r1_) + (r2_ + r3_);                                      \
    rs += __shfl_xor(rs, 32);                                                  \
    l_i += rs;                                                                 \
    /* 4: issue V(kt+1) load (written to LDS at step 7) */                     \
    if (kt_ < 63) {                                                            \
      svh = *reinterpret_cast<const bfrag*>(vph);                              \
      svl = *reinterpret_cast<const bfrag*>(vpl);                              \
      vph += KSTEP; vpl += KSTEP;                                              \
    }                                                                          \
    /* 5: pack P hi (fp16, RTZ) + permlane32_swap frag build — no lo pack */   \
    unsigned ph_[8];                                                           \
    _Pragma("unroll") for (int i = 0; i < 8; ++i)                              \
        ph_[i] = cvt_pkrtz_u(p[2 * i], p[2 * i + 1]);                          \
    permswap(ph_[0], ph_[2]); permswap(ph_[1], ph_[3]);                        \
    permswap(ph_[4], ph_[6]); permswap(ph_[5], ph_[7]);                        \
    union U4 { unsigned u[4]; hfrag f; };                                      \
    U4 f0h, f1h;                                                               \
    f0h.u[0] = ph_[0]; f0h.u[1] = ph_[1]; f0h.u[2] = ph_[2]; f0h.u[3] = ph_[3];\
    f1h.u[0] = ph_[4]; f1h.u[1] = ph_[5]; f1h.u[2] = ph_[6]; f1h.u[3] = ph_[7];\
    /* 6: PV(kt) from LDS[cur_], rho rows; 2-pass: (Vh+Vl)·Ph */               \
    __builtin_amdgcn_s_setprio(1);                                             \
    _Pragma("unroll") for (int c = 0; c < 2; ++c) {                            \
      hfrag pF = c ? f1h.f : f0h.f;                                            \
      hfrag vh0 = *reinterpret_cast<const hfrag*>(&Vth[cur_][rA][c * 16 + hi * 8]); \
      hfrag vl0 = *reinterpret_cast<const hfrag*>(&Vtl[cur_][rA][c * 16 + hi * 8]); \
      hfrag vh1 = *reinterpret_cast<const hfrag*>(&Vth[cur_][rB][c * 16 + hi * 8]); \
      hfrag vl1 = *reinterpret_cast<const hfrag*>(&Vtl[cur_][rB][c * 16 + hi * 8]); \
      oA0 = MFMA32H(vh0, pF, oA0);                                             \
      oB0 = MFMA32H(vl0, pF, oB0);                                             \
      oA1 = MFMA32H(vh1, pF, oA1);                                             \
      oB1 = MFMA32H(vl1, pF, oB1);                                             \
    }                                                                          \
    __builtin_amdgcn_s_setprio(0);                                             \
    /* 7: write staged V(kt+1) (static element, rho rows), barrier */          \
    if (kt_ < 63) {                                                            \
      _Pragma("unroll") for (int j2 = 0; j2 < 8; ++j2) {                       \
        int row = sc * 8 + ((j2 + sc) & 7);                                    \
        Vth[cur_ ^ 1][row][skp] = (unsigned short)svh[j2];                     \
        Vtl[cur_ ^ 1][row][skp] = (unsigned short)svl[j2];                     \
      }                                                                        \
      __syncthreads();                                                         \
    }                                                                          \
  } while (0)

  for (int kt = 0; kt < 64; kt += 2) {
    ATTN_ITER(kt, sA, sB);
    ATTN_ITER(kt + 1, sB, sA);
  }
#undef ATTN_ITER

  // ---- epilogue: combine chains, normalize, store fp32 [B,S,H*Dh] ----
  float inv = 1.0f / l_i;
  const size_t orow = (bbase + q0 + q) * 1024 + hoff;
#pragma unroll
  for (int dblk = 0; dblk < 2; ++dblk) {
#pragma unroll
    for (int rg = 0; rg < 4; ++rg) {
      float4 o;
      if (dblk == 0) {
        o.x = (oA0[rg * 4 + 0] + oB0[rg * 4 + 0]) * inv;
        o.y = (oA0[rg * 4 + 1] + oB0[rg * 4 + 1]) * inv;
        o.z = (oA0[rg * 4 + 2] + oB0[rg * 4 + 2]) * inv;
        o.w = (oA0[rg * 4 + 3] + oB0[rg * 4 + 3]) * inv;
      } else {
        o.x = (oA1[rg * 4 + 0] + oB1[rg * 4 + 0]) * inv;
        o.y = (oA1[rg * 4 + 1] + oB1[rg * 4 + 1]) * inv;
        o.z = (oA1[rg * 4 + 2] + oB1[rg * 4 + 2]) * inv;
        o.w = (oA1[rg * 4 + 3] + oB1[rg * 4 + 3]) * inv;
      }
      *reinterpret_cast<float4*>(out + orow + dblk * 32 + rg * 8 + hi * 4) = o;
    }
  }
}

// ---------------------------------------------------------------------------
// Workspace layout (72.25 MiB footprint; wql/wol regions now unused):
//   @ 0        : x_q fp16-codes (8 MiB)     @ 8 MiB : s_x (128 KiB)
//   @ 8.25 MiB : WTqkv fp16 (6 MiB)         @ 20.25 : WTout fp16 (2 MiB)
//   @ 24.25    : qkvh fp16 (24 MiB)         @ 48.25 : qkvl fp16 (24 MiB)
// ---------------------------------------------------------------------------
extern "C" void kernel_launch(void* const* d_in, const int* in_sizes, int n_in,
                              void* d_out, int out_size, void* d_ws, size_t ws_size,
                              hipStream_t stream) {
  const float* x     = (const float*)d_in[0];
  const float* W_qkv = (const float*)d_in[1];
  const float* b_qkv = (const float*)d_in[2];
  const float* W_out = (const float*)d_in[3];
  const float* b_out = (const float*)d_in[4];
  float* y = (float*)d_out;

  char* ws = (char*)d_ws;
  const size_t MB = 1u << 20;
  unsigned short* x_q   = (unsigned short*)(ws);
  float*          s_x   = (float*)(ws + 8 * MB);
  unsigned short* wqh   = (unsigned short*)(ws + 8 * MB + 256 * 1024);
  unsigned short* woh   = (unsigned short*)(ws + 20 * MB + 256 * 1024);
  unsigned short* qkvh  = (unsigned short*)(ws + 24 * MB + 256 * 1024);
  unsigned short* qkvl  = (unsigned short*)(ws + 48 * MB + 256 * 1024);

  // 1. quantize activations (fp16 codes + scales) and weights (fp16 dequant)
  quant_x<<<8192, 256, 0, stream>>>(x, x_q, s_x, 32768);
  quant_w_t<<<dim3(24, 16), 256, 0, stream>>>(W_qkv, wqh, 1024, 3072);
  quant_w_t<<<dim3(8, 16), 256, 0, stream>>>(W_out, woh, 1024, 1024);

  // 2. QKV projection (fp16 1-pass MFMA) -> fp16 hi/lo split
  gemm_q<4, true><<<768, 256, 0, stream>>>(x_q, s_x, wqh, b_qkv,
                                           nullptr, qkvh, qkvl, 4096, 3072, 1024);

  // 3. fp16-split 2-pass flash attention (XCD-remapped 1-D grid)
  attn_mfma32<<<512, 256, 0, stream>>>(qkvh, qkvl, y);

  // 4. quantize attention output (reuse x_q / s_x buffers)
  quant_x<<<8192, 256, 0, stream>>>(y, x_q, s_x, 32768);

  // 5. output projection (fp16 1-pass): 64x128 tiles -> 512 blocks
  gemm_q<2, false><<<512, 256, 0, stream>>>(x_q, s_x, woh, b_out,
                                            y, nullptr, nullptr, 4096, 1024, 1024);
}

// Round 20
// 177.426 us; speedup vs baseline: 1.7188x; 1.1479x over previous
//
#include <hip/hip_runtime.h>
#include <cstdint>
#include <cstddef>

typedef __attribute__((ext_vector_type(8))) short bfrag;      // 8x16-bit (4 VGPR)
typedef __attribute__((ext_vector_type(8))) _Float16 hfrag;   // 8 f16 (4 VGPR)
typedef __attribute__((ext_vector_type(2))) __fp16 fp16x2;    // cvt_pkrtz result type
typedef __attribute__((ext_vector_type(4))) float f4;         // 16x16 MFMA C/D
typedef __attribute__((ext_vector_type(16))) float f16v;      // 32x32 MFMA C/D

#define MFMA16H(a, b, c) __builtin_amdgcn_mfma_f32_16x16x32_f16(a, b, c, 0, 0, 0)
#define MFMA32H(a, b, c) __builtin_amdgcn_mfma_f32_32x32x16_f16(a, b, c, 0, 0, 0)

// ---------------------------------------------------------------------------
// fp16 helpers.
// ---------------------------------------------------------------------------
__device__ __forceinline__ unsigned cvt_pkrtz_u(float a, float b) {
  union { fp16x2 h; unsigned u; } c;
  c.h = __builtin_amdgcn_cvt_pkrtz(a, b);
  return c.u;
}
__device__ __forceinline__ unsigned short f2h_bits(float x) {  // RNE
  _Float16 h = (_Float16)x;
  union { _Float16 h; unsigned short u; } c;
  c.h = h;
  return c.u;
}
// One-instruction cross-half exchange: a' = [a_lo | b_lo], b' = [a_hi | b_hi].
__device__ __forceinline__ void permswap(unsigned& a, unsigned& b) {
  auto r = __builtin_amdgcn_permlane32_swap((int)a, (int)b, false, false);
  a = (unsigned)r[0];
  b = (unsigned)r[1];
}
// Async global->LDS, 16B per lane. Dest is wave-uniform base + lane*16.
__device__ __forceinline__ void gl16(const unsigned short* g, unsigned short* l) {
  __builtin_amdgcn_global_load_lds(
      (const __attribute__((address_space(1))) unsigned int*)g,
      (__attribute__((address_space(3))) unsigned int*)l, 16, 0, 0);
}

// ---------------------------------------------------------------------------
// Software-exact OCP e4m3fn rounding (RTNE via magic-add; matches ml_dtypes
// bit-exact incl. subnormal grid 2^-9 and the 448-saturation region).
// ---------------------------------------------------------------------------
__device__ __forceinline__ float qd_e4m3(float v) {
  float a = fabsf(v);
  unsigned u = __float_as_uint(a);
  int e = (int)(u >> 23) - 127;
  int k = e - 3;
  if (k < -9) k = -9;
  float big = __uint_as_float((unsigned)(k + 150) << 23);  // 2^(k+23)
  float r = (a + big) - big;
  return __builtin_copysignf(r, v);
}

// ---------------------------------------------------------------------------
// Activation quant: per 128-block, emit e4m3 CODES as FP16 (exact) + scale.
// ---------------------------------------------------------------------------
__global__ __launch_bounds__(256) void quant_x(const float* __restrict__ src,
                                               unsigned short* __restrict__ q,
                                               float* __restrict__ s,
                                               int nblk) {
  int gid = blockIdx.x * 256 + threadIdx.x;
  int wid = gid >> 6;
  int lane = gid & 63;
  if (wid >= nblk) return;
  size_t off = (size_t)wid * 128 + lane * 2;
  float2 xv = *reinterpret_cast<const float2*>(src + off);
  float m = fmaxf(fabsf(xv.x), fabsf(xv.y));
#pragma unroll
  for (int d = 32; d > 0; d >>= 1) m = fmaxf(m, __shfl_xor(m, d));
  float scale = fmaxf(m / 448.0f, 1e-12f);
  unsigned short q0 = f2h_bits(qd_e4m3(xv.x / scale));  // exact: e4m3 ⊂ fp16
  unsigned short q1 = f2h_bits(qd_e4m3(xv.y / scale));
  *reinterpret_cast<unsigned*>(q + off) = (unsigned)q0 | ((unsigned)q1 << 16);
  if (lane == 0) s[wid] = scale;
}

// ---------------------------------------------------------------------------
// Weight quant + dequant -> FP16 (RNE, rel err <= 2^-12) + TRANSPOSE.
// ---------------------------------------------------------------------------
__global__ __launch_bounds__(256) void quant_w_t(const float* __restrict__ W,
                                                 unsigned short* __restrict__ WT,
                                                 int K, int N) {
  __shared__ __align__(16) unsigned short Ht[128][72];
  const int tid = threadIdx.x;
  const int w = tid >> 6, l = tid & 63;
  const int k0 = blockIdx.y * 64, n0 = blockIdx.x * 128;
#pragma unroll 4
  for (int i = 0; i < 16; ++i) {
    int kl = w * 16 + i;
    float2 xv = *reinterpret_cast<const float2*>(&W[(size_t)(k0 + kl) * N + n0 + l * 2]);
    float m = fmaxf(fabsf(xv.x), fabsf(xv.y));
#pragma unroll
    for (int d = 32; d > 0; d >>= 1) m = fmaxf(m, __shfl_xor(m, d));
    float scale = fmaxf(m / 448.0f, 1e-12f);
    Ht[l * 2][kl]     = f2h_bits(qd_e4m3(xv.x / scale) * scale);
    Ht[l * 2 + 1][kl] = f2h_bits(qd_e4m3(xv.y / scale) * scale);
  }
  __syncthreads();
  const int n = tid & 127, hs = tid >> 7;   // thread -> (n-row, k-half)
  unsigned short* dst = WT + (size_t)(n0 + n) * K + k0 + hs * 32;
#pragma unroll
  for (int j = 0; j < 4; ++j)
    *reinterpret_cast<bfrag*>(dst + j * 8) =
        *reinterpret_cast<const bfrag*>(&Ht[n][hs * 32 + j * 8]);
}

// ---------------------------------------------------------------------------
// Quantization-aware MFMA GEMM, FP16 1-PASS. SPLIT=true epilogue emits a
// SINGLE fp16 RNE stream (round 20: attention is 1-pass fp16 throughout).
// ---------------------------------------------------------------------------
template <int MF, bool SPLIT>
__global__ __launch_bounds__(256, 2) void gemm_q(const unsigned short* __restrict__ Aq,
                                                 const float* __restrict__ As,
                                                 const unsigned short* __restrict__ WT,
                                                 const float* __restrict__ bias,
                                                 float* __restrict__ Cf,
                                                 unsigned short* __restrict__ C16,
                                                 int M, int N, int K) {
  constexpr int MT = MF * 32;
  __shared__ __align__(16) unsigned short Al[MT][64];
  __shared__ __align__(16) unsigned short Bh[128][64];
  __shared__ float Ss[MT][8];
  const int tid = threadIdx.x;
  const int w = tid >> 6, l = tid & 63;
  const int lr = l & 15, lg = l >> 4;
  const int nbx = N >> 7;
  const int nwg = nbx * (M / MT);
  const int q8 = nwg >> 3;
  const int swz = ((int)blockIdx.x & 7) * q8 + ((int)blockIdx.x >> 3);
  const int row0 = (swz / nbx) * MT, col0 = (swz % nbx) << 7;
  const int wr = (w >> 1) * (MT / 2), wc = (w & 1) * 64;
  const int xsw = (lr & 7) * 8;        // read-side XOR (short units)

  if (MF == 4) {
    int r = tid >> 1, c0 = (tid & 1) * 4;
    *reinterpret_cast<float4*>(&Ss[r][c0]) =
        *reinterpret_cast<const float4*>(&As[(size_t)(row0 + r) * 8 + c0]);
  } else {
    int r = tid >> 2, c0 = (tid & 3) * 2;
    *reinterpret_cast<float2*>(&Ss[r][c0]) =
        *reinterpret_cast<const float2*>(&As[(size_t)(row0 + r) * 8 + c0]);
  }

  f4 acc[MF][4], seg[MF][4];
#pragma unroll
  for (int i = 0; i < MF; ++i)
#pragma unroll
    for (int j = 0; j < 4; ++j)
#pragma unroll
      for (int c = 0; c < 4; ++c) {
        acc[i][j][c] = 0.f;
        seg[i][j][c] = 0.f;
      }

  const int lrow = l >> 3;             // 0..7
  const int jch = (l & 7) ^ lrow;      // inverse-swizzled source chunk
  const unsigned short* pA = Aq + (size_t)(row0 + w * (MT / 4) + lrow) * K + jch * 8;
  const unsigned short* pH = WT + (size_t)(col0 + w * 32 + lrow) * K + jch * 8;
  unsigned short* dA = &Al[0][0] + w * (MT / 4) * 64;
  unsigned short* dH = &Bh[0][0] + w * 2048;

  const int niter = K >> 6;
  for (int it = 0; it < niter; ++it) {
    const int k0 = it << 6;
    __syncthreads();
#pragma unroll
    for (int ii = 0; ii < MF; ++ii)
      gl16(pA + (size_t)ii * 8 * K + k0, dA + ii * 512);
#pragma unroll
    for (int ii = 0; ii < 4; ++ii)
      gl16(pH + (size_t)ii * 8 * K + k0, dH + ii * 512);
    __syncthreads();

#pragma unroll
    for (int ks = 0; ks < 2; ++ks) {
      hfrag af[MF];
#pragma unroll
      for (int mf = 0; mf < MF; ++mf)
        af[mf] = *reinterpret_cast<const hfrag*>(
            &Al[0][0] + (wr + mf * 16 + lr) * 64 + ((ks * 32 + lg * 8) ^ xsw));
#pragma unroll
      for (int nf = 0; nf < 4; ++nf) {
        hfrag bh = *reinterpret_cast<const hfrag*>(
            &Bh[0][0] + (wc + nf * 16 + lr) * 64 + ((ks * 32 + lg * 8) ^ xsw));
#pragma unroll
        for (int mf = 0; mf < MF; ++mf)
          seg[mf][nf] = MFMA16H(af[mf], bh, seg[mf][nf]);
      }
    }

    if (it & 1) {
      const int kb = it >> 1;
#pragma unroll
      for (int mf = 0; mf < MF; ++mf) {
        float sv[4];
#pragma unroll
        for (int r = 0; r < 4; ++r) sv[r] = Ss[wr + mf * 16 + lg * 4 + r][kb];
#pragma unroll
        for (int nf = 0; nf < 4; ++nf)
#pragma unroll
          for (int r = 0; r < 4; ++r) {
            acc[mf][nf][r] += sv[r] * seg[mf][nf][r];
            seg[mf][nf][r] = 0.f;
          }
      }
    }
  }

#pragma unroll
  for (int mf = 0; mf < MF; ++mf) {
#pragma unroll
    for (int r = 0; r < 4; ++r) {
      const int m = row0 + wr + mf * 16 + lg * 4 + r;
#pragma unroll
      for (int nf = 0; nf < 4; ++nf) {
        const int col = col0 + wc + nf * 16 + lr;
        float o = acc[mf][nf][r] + bias[col];
        if (SPLIT) {
          C16[(size_t)m * N + col] = f2h_bits(o);  // single fp16 stream
        } else {
          Cf[(size_t)m * N + col] = o;
        }
      }
    }
  }
}

// ---------------------------------------------------------------------------
// Swapped-operand 32x32 MFMA flash attention — SINGLE-STREAM FP16 1-PASS
// (round 20): qkv is one fp16 RNE array. QK = Kh·Qh (4 MFMA), PV = Vh·Ph
// (4 MFMA) -> 8 MFMA/iter (was 16). LDS halves (one V buffer). XCD-aware
// grid + rho V-staging + permlane pack + QK||softmax pipeline + defer-max.
// ---------------------------------------------------------------------------
__global__ __launch_bounds__(256, 2) void attn_mfma32(const unsigned short* __restrict__ qkv,
                                                      float* __restrict__ out) {
  __shared__ __align__(16) unsigned short Vth[2][64][40];  // V^T: [buf][rho(d)][kpos]
  const int tid = threadIdx.x;
  const int w = tid >> 6, l = tid & 63;
  const int q = l & 31;
  const int hi = l >> 5;
  // XCD-aware decode: XCD k owns bh in {4k..4k+3} (2 MB KV -> L2-resident)
  const int lin = (int)blockIdx.x;
  const int xcd = lin & 7, j = lin >> 3;
  const int bh = 4 * xcd + (j >> 4);
  const int qt = j & 15;
  const int q0 = qt * 128 + w * 32;
  const int b = bh >> 4, h = bh & 15;
  const size_t bbase = (size_t)b * 2048;
  const size_t hoff = (size_t)h * 64;

  const int rA = (q & 24) | ((q + (q >> 3)) & 7);              // d = q
  const int rB = 32 + ((q & 24) | ((q + 4 + (q >> 3)) & 7));   // d = 32+q

  hfrag qh[4];
  {
    const size_t qrow = (bbase + q0 + q) * 3072 + hoff + hi * 8;
#pragma unroll
    for (int f = 0; f < 4; ++f)
      qh[f] = *reinterpret_cast<const hfrag*>(qkv + qrow + f * 16);
  }

  const int skp = tid >> 3;   // 0..31 (kpos)
  const int sc = tid & 7;     // 0..7  (d-chunk of 8)

  const unsigned short* kph = qkv + (bbase + q) * 3072 + 1024 + hoff + hi * 8;
  const unsigned short* vph = qkv + (bbase + skp) * 3072 + 2048 + hoff + sc * 8;
  const size_t KSTEP = (size_t)32 * 3072;

  hfrag kh[4];
  bfrag svh;

  // ---- prologue: K(0), V(0)->LDS0, QK(0)->sA, K(1) ----
#pragma unroll
  for (int f = 0; f < 4; ++f)
    kh[f] = *reinterpret_cast<const hfrag*>(kph + f * 16);
  svh = *reinterpret_cast<const bfrag*>(vph);
  vph += KSTEP;
#pragma unroll
  for (int j2 = 0; j2 < 8; ++j2) {  // static element j2 -> row rho(sc*8+j2)
    int row = sc * 8 + ((j2 + sc) & 7);
    Vth[0][row][skp] = (unsigned short)svh[j2];
  }
  f16v sA, sB;
#pragma unroll
  for (int r = 0; r < 16; ++r) sA[r] = 0.f;
  __builtin_amdgcn_s_setprio(1);
#pragma unroll
  for (int f = 0; f < 4; ++f) sA = MFMA32H(kh[f], qh[f], sA);
  __builtin_amdgcn_s_setprio(0);
  kph += KSTEP;
#pragma unroll
  for (int f = 0; f < 4; ++f)
    kh[f] = *reinterpret_cast<const hfrag*>(kph + f * 16);
  __syncthreads();

  f16v oA0, oA1;
#pragma unroll
  for (int r = 0; r < 16; ++r) { oA0[r] = 0.f; oA1[r] = 0.f; }
  float m_i = -1e30f, l_i = 0.f;

#define ATTN_ITER(KT, SCUR, SNXT)                                              \
  do {                                                                         \
    const int kt_ = (KT);                                                      \
    const int cur_ = kt_ & 1;                                                  \
    /* 1: issue QK(kt+1) into SNXT (1-pass f16; overlaps softmax below) */     \
    if (kt_ < 63) {                                                            \
      _Pragma("unroll") for (int r = 0; r < 16; ++r) SNXT[r] = 0.f;            \
      __builtin_amdgcn_s_setprio(1);                                           \
      _Pragma("unroll") for (int f = 0; f < 4; ++f)                            \
          SNXT = MFMA32H(kh[f], qh[f], SNXT);                                  \
      __builtin_amdgcn_s_setprio(0);                                           \
    }                                                                          \
    /* 2: K(kt+2) loads */                                                     \
    if (kt_ < 62) {                                                            \
      kph += KSTEP;                                                            \
      _Pragma("unroll") for (int f = 0; f < 4; ++f)                            \
          kh[f] = *reinterpret_cast<const hfrag*>(kph + f * 16);               \
    }                                                                          \
    /* 3: softmax on SCUR (VALU — overlaps step-1 MFMAs) */                    \
    float a0 = fmaxf(SCUR[0], SCUR[1]), a1 = fmaxf(SCUR[2], SCUR[3]);          \
    float a2 = fmaxf(SCUR[4], SCUR[5]), a3 = fmaxf(SCUR[6], SCUR[7]);          \
    float a4 = fmaxf(SCUR[8], SCUR[9]), a5 = fmaxf(SCUR[10], SCUR[11]);        \
    float a6 = fmaxf(SCUR[12], SCUR[13]), a7 = fmaxf(SCUR[14], SCUR[15]);      \
    float b0_ = fmaxf(a0, a1), b1_ = fmaxf(a2, a3);                            \
    float b2_ = fmaxf(a4, a5), b3_ = fmaxf(a6, a7);                            \
    float mt = fmaxf(fmaxf(b0_, b1_), fmaxf(b2_, b3_));                        \
    mt = fmaxf(mt, __shfl_xor(mt, 32));                                        \
    mt *= 0.125f;                                                              \
    if (!__all(mt <= m_i)) { /* defer-max: THR=0 is bit-exact */               \
      float mn = fmaxf(m_i, mt);                                               \
      float corr = __expf(m_i - mn);                                           \
      m_i = mn;                                                                \
      l_i *= corr;                                                             \
      _Pragma("unroll") for (int r = 0; r < 16; ++r) {                         \
        oA0[r] *= corr; oA1[r] *= corr;                                        \
      }                                                                        \
    }                                                                          \
    float p[16];                                                               \
    _Pragma("unroll") for (int r = 0; r < 16; ++r)                             \
        p[r] = __expf(fmaf(SCUR[r], 0.125f, -m_i));                            \
    float r0_ = (p[0] + p[1]) + (p[2] + p[3]);                                 \
    float r1_ = (p[4] + p[5]) + (p[6] + p[7]);                                 \
    float r2_ = (p[8] + p[9]) + (p[10] + p[11]);                               \
    float r3_ = (p[12] + p[13]) + (p[14] + p[15]);                             \
    float rs = (r0_ + r1_) + (r2_ + r3_);                                      \
    rs += __shfl_xor(rs, 32);                                                  \
    l_i += rs;                                                                 \
    /* 4: issue V(kt+1) load (written to LDS at step 7) */                     \
    if (kt_ < 63) {                                                            \
      svh = *reinterpret_cast<const bfrag*>(vph);                              \
      vph += KSTEP;                                                            \
    }                                                                          \
    /* 5: pack P (fp16, RTZ) + permlane32_swap frag build */                   \
    unsigned ph_[8];                                                           \
    _Pragma("unroll") for (int i = 0; i < 8; ++i)                              \
        ph_[i] = cvt_pkrtz_u(p[2 * i], p[2 * i + 1]);                          \
    permswap(ph_[0], ph_[2]); permswap(ph_[1], ph_[3]);                        \
    permswap(ph_[4], ph_[6]); permswap(ph_[5], ph_[7]);                        \
    union U4 { unsigned u[4]; hfrag f; };                                      \
    U4 f0h, f1h;                                                               \
    f0h.u[0] = ph_[0]; f0h.u[1] = ph_[1]; f0h.u[2] = ph_[2]; f0h.u[3] = ph_[3];\
    f1h.u[0] = ph_[4]; f1h.u[1] = ph_[5]; f1h.u[2] = ph_[6]; f1h.u[3] = ph_[7];\
    /* 6: PV(kt) from LDS[cur_], rho rows; 1-pass Vh·Ph */                     \
    __builtin_amdgcn_s_setprio(1);                                             \
    _Pragma("unroll") for (int c = 0; c < 2; ++c) {                            \
      hfrag pF = c ? f1h.f : f0h.f;                                            \
      hfrag vh0 = *reinterpret_cast<const hfrag*>(&Vth[cur_][rA][c * 16 + hi * 8]); \
      hfrag vh1 = *reinterpret_cast<const hfrag*>(&Vth[cur_][rB][c * 16 + hi * 8]); \
      oA0 = MFMA32H(vh0, pF, oA0);                                             \
      oA1 = MFMA32H(vh1, pF, oA1);                                             \
    }                                                                          \
    __builtin_amdgcn_s_setprio(0);                                             \
    /* 7: write staged V(kt+1) (static element, rho rows), barrier */          \
    if (kt_ < 63) {                                                            \
      _Pragma("unroll") for (int j2 = 0; j2 < 8; ++j2) {                       \
        int row = sc * 8 + ((j2 + sc) & 7);                                    \
        Vth[cur_ ^ 1][row][skp] = (unsigned short)svh[j2];                     \
      }                                                                        \
      __syncthreads();                                                         \
    }                                                                          \
  } while (0)

  for (int kt = 0; kt < 64; kt += 2) {
    ATTN_ITER(kt, sA, sB);
    ATTN_ITER(kt + 1, sB, sA);
  }
#undef ATTN_ITER

  // ---- epilogue: normalize, store fp32 [B,S,H*Dh] ----
  float inv = 1.0f / l_i;
  const size_t orow = (bbase + q0 + q) * 1024 + hoff;
#pragma unroll
  for (int dblk = 0; dblk < 2; ++dblk) {
#pragma unroll
    for (int rg = 0; rg < 4; ++rg) {
      float4 o;
      if (dblk == 0) {
        o.x = oA0[rg * 4 + 0] * inv;
        o.y = oA0[rg * 4 + 1] * inv;
        o.z = oA0[rg * 4 + 2] * inv;
        o.w = oA0[rg * 4 + 3] * inv;
      } else {
        o.x = oA1[rg * 4 + 0] * inv;
        o.y = oA1[rg * 4 + 1] * inv;
        o.z = oA1[rg * 4 + 2] * inv;
        o.w = oA1[rg * 4 + 3] * inv;
      }
      *reinterpret_cast<float4*>(out + orow + dblk * 32 + rg * 8 + hi * 4) = o;
    }
  }
}

// ---------------------------------------------------------------------------
// Workspace layout (48.25 MiB used):
//   @ 0        : x_q fp16-codes (8 MiB)     @ 8 MiB : s_x (128 KiB)
//   @ 8.25 MiB : WTqkv fp16 (6 MiB)         @ 20.25 : WTout fp16 (2 MiB)
//   @ 24.25    : qkv fp16 single-stream (24 MiB)
// ---------------------------------------------------------------------------
extern "C" void kernel_launch(void* const* d_in, const int* in_sizes, int n_in,
                              void* d_out, int out_size, void* d_ws, size_t ws_size,
                              hipStream_t stream) {
  const float* x     = (const float*)d_in[0];
  const float* W_qkv = (const float*)d_in[1];
  const float* b_qkv = (const float*)d_in[2];
  const float* W_out = (const float*)d_in[3];
  const float* b_out = (const float*)d_in[4];
  float* y = (float*)d_out;

  char* ws = (char*)d_ws;
  const size_t MB = 1u << 20;
  unsigned short* x_q   = (unsigned short*)(ws);
  float*          s_x   = (float*)(ws + 8 * MB);
  unsigned short* wqh   = (unsigned short*)(ws + 8 * MB + 256 * 1024);
  unsigned short* woh   = (unsigned short*)(ws + 20 * MB + 256 * 1024);
  unsigned short* qkv   = (unsigned short*)(ws + 24 * MB + 256 * 1024);

  // 1. quantize activations (fp16 codes + scales) and weights (fp16 dequant)
  quant_x<<<8192, 256, 0, stream>>>(x, x_q, s_x, 32768);
  quant_w_t<<<dim3(24, 16), 256, 0, stream>>>(W_qkv, wqh, 1024, 3072);
  quant_w_t<<<dim3(8, 16), 256, 0, stream>>>(W_out, woh, 1024, 1024);

  // 2. QKV projection (fp16 1-pass MFMA) -> single fp16 stream
  gemm_q<4, true><<<768, 256, 0, stream>>>(x_q, s_x, wqh, b_qkv,
                                           nullptr, qkv, 4096, 3072, 1024);

  // 3. single-stream fp16 1-pass flash attention (XCD-remapped 1-D grid)
  attn_mfma32<<<512, 256, 0, stream>>>(qkv, y);

  // 4. quantize attention output (reuse x_q / s_x buffers)
  quant_x<<<8192, 256, 0, stream>>>(y, x_q, s_x, 32768);

  // 5. output projection (fp16 1-pass): 64x128 tiles -> 512 blocks
  gemm_q<2, false><<<512, 256, 0, stream>>>(x_q, s_x, woh, b_out,
                                            y, nullptr, 4096, 1024, 1024);
}